// Round 6
// baseline (840.724 us; speedup 1.0000x reference)
//
#include <hip/hip_runtime.h>
#include <hip/hip_bf16.h>
#include <math.h>

#define Bk 8
#define Nk 10000
#define Hk 64
#define Lk 4
#define Rk 3
#define Ek 200000
#define FPk 2048

typedef unsigned short u16;
typedef unsigned int   u32;
typedef __attribute__((ext_vector_type(8))) short bf16x8;
typedef __attribute__((ext_vector_type(4))) float f32x4;

__device__ __forceinline__ float bf2f(u16 u){
    union{u32 i; float f;} v; v.i = (u32)u << 16; return v.f;
}
__device__ __forceinline__ u16 f2bf(float f){      // round-to-nearest-even
    union{u32 i; float f;} v; v.f = f;
    u32 r = v.i + 0x7fffu + ((v.i >> 16) & 1u);
    return (u16)(r >> 16);
}

// ---------------------------------------------------------------------------
// CSR build
// ---------------------------------------------------------------------------
__global__ void k_zero(int* p, int n){
    int i = blockIdx.x*256 + threadIdx.x;
    if(i < n) p[i] = 0;
}

__global__ void k_count(const int* edge_index, int* deg){
    int idx = blockIdx.x*256 + threadIdx.x;
    if(idx >= Rk*Ek) return;
    int r = idx / Ek, e = idx % Ek;
    int dst = edge_index[r*2*Ek + Ek + e];
    atomicAdd(&deg[r*Nk + dst], 1);
}

__global__ void k_scan(const int* deg, int* offs, int* cursor){
    int r = blockIdx.x;
    __shared__ int s[1024];
    __shared__ int carry;
    if(threadIdx.x == 0) carry = 0;
    __syncthreads();
    for(int base = 0; base < Nk; base += 1024){
        int i = base + threadIdx.x;
        int v = (i < Nk) ? deg[r*Nk + i] : 0;
        s[threadIdx.x] = v;
        __syncthreads();
        for(int d = 1; d < 1024; d <<= 1){
            int t = (threadIdx.x >= d) ? s[threadIdx.x - d] : 0;
            __syncthreads();
            s[threadIdx.x] += t;
            __syncthreads();
        }
        int incl = s[threadIdx.x];
        int excl = carry + incl - v;
        if(i < Nk){ offs[r*(Nk+1)+i] = excl; cursor[r*Nk+i] = excl; }
        __syncthreads();
        if(threadIdx.x == 1023) carry += s[1023];
        __syncthreads();
    }
    if(threadIdx.x == 0) offs[r*(Nk+1)+Nk] = carry;
}

// pack each edge as {src*128 (byte offset into a 64-feat bf16 row), w bits}
__global__ void k_fill(const int* edge_index, const float* edge_weight,
                       int* cursor, int2* epack){
    int idx = blockIdx.x*256 + threadIdx.x;
    if(idx >= Rk*Ek) return;
    int r = idx / Ek, e = idx % Ek;
    int src = edge_index[r*2*Ek + e];
    int dst = edge_index[r*2*Ek + Ek + e];
    int pos = atomicAdd(&cursor[r*Nk + dst], 1);
    epack[(size_t)r*Ek + pos] = make_int2(src << 7, __float_as_int(edge_weight[r*Ek + e]));
}

// ---------------------------------------------------------------------------
// Weight prep: W -> MFMA B-operand layout, split hi/lo bf16 (fp32-accurate).
// ---------------------------------------------------------------------------
__global__ void k_wprep(const float* __restrict__ Wself, const float* __restrict__ Wrel,
                        u16* __restrict__ wt_hi, u16* __restrict__ wt_lo){
    int idx = blockIdx.x*256 + threadIdx.x;
    if(idx >= Lk*4*2*4*64*8) return;
    int j    = idx & 7;
    int lane = (idx >> 3) & 63;
    int jt   = (idx >> 9) & 3;
    int kc   = (idx >> 11) & 1;
    int mt   = (idx >> 12) & 3;
    int l    = idx >> 14;
    int k    = kc*32 + (lane >> 4)*8 + j;
    int col  = jt*16 + (lane & 15);
    float w = (mt == 0) ? Wself[(l*64 + k)*64 + col]
                        : Wrel[((l*3 + (mt-1))*64 + k)*64 + col];
    u16 hi = f2bf(w);
    u16 lo = f2bf(w - bf2f(hi));
    wt_hi[idx] = hi;
    wt_lo[idx] = lo;
}

// ---------------------------------------------------------------------------
// FiLM
// ---------------------------------------------------------------------------
__global__ void k_film1(const float* fp, const float* W1, const float* b1, float* hid){
    int b = blockIdx.x >> 6, h = blockIdx.x & 63;
    const float* fpb = fp + b*FPk;
    float acc = 0.f;
    for(int k = threadIdx.x; k < FPk; k += 256)
        acc += fpb[k] * W1[k*64 + h];
    __shared__ float red[256];
    red[threadIdx.x] = acc;
    __syncthreads();
    for(int s = 128; s >= 1; s >>= 1){
        if(threadIdx.x < s) red[threadIdx.x] += red[threadIdx.x + s];
        __syncthreads();
    }
    if(threadIdx.x == 0) hid[b*64 + h] = fmaxf(red[0] + b1[h], 0.f);
}

__global__ void k_film2(const float* hid, const float* W2, const float* b2,
                        float* g1p, float* beta){
    int b = blockIdx.x, j = threadIdx.x;   // 128 threads
    float acc = b2[j];
    for(int k = 0; k < 64; ++k)
        acc += hid[b*64 + k] * W2[k*128 + j];
    if(j < 64) g1p[b*64 + j] = 1.f + tanhf(acc);
    else       beta[b*64 + j - 64] = acc;
}

// ---------------------------------------------------------------------------
// x0 (bf16)
// ---------------------------------------------------------------------------
__global__ void k_init(const float* ctl, const float* dt, const int* cell_idx,
                       const float* W_se, const float* b_se, const float* cell_emb,
                       const float* g1p, const float* beta, u16* xh){
    const size_t total = (size_t)Bk*Nk*64;
    for(size_t i = (size_t)blockIdx.x*256 + threadIdx.x; i < total; i += (size_t)gridDim.x*256){
        int h = (int)(i & 63);
        size_t bn = i >> 6;
        int b = (int)(bn / Nk);
        float w = W_se[h], bs = b_se[h];
        float v = fmaxf(ctl[bn]*w + bs, 0.f) + fmaxf(dt[bn]*w + bs, 0.f)
                + cell_emb[cell_idx[b]*64 + h];
        xh[i] = f2bf(v * g1p[b*64 + h] + beta[b*64 + h]);
    }
}

// ---------------------------------------------------------------------------
// agg (bf16): one wave per (r,dst), b = blockIdx%8 (XCD round-robin keeps each
// XCD's gathers on one 1.28MB batch slice = L2-resident).
// Adjacency via wave-uniform (readfirstlane) loads -> scalar pipe; gather is
// saddr-form global_load_ushort. ~2 VALU per edge-visit.
// ---------------------------------------------------------------------------
__global__ __launch_bounds__(256) void k_agg(const u16* __restrict__ xh,
                      const int* __restrict__ offs, const int2* __restrict__ epack,
                      u16* __restrict__ aggh){
    int b   = blockIdx.x & 7;
    int grp = blockIdx.x >> 3;                       // 0..7499
    int wid = grp*4 + (threadIdx.x >> 6);            // 0..29999 = (r,dst)
    int lane = threadIdx.x & 63;
    int r = wid / Nk, dst = wid % Nk;
    int o0 = __builtin_amdgcn_readfirstlane(offs[r*(Nk+1) + dst]);
    int o1 = __builtin_amdgcn_readfirstlane(offs[r*(Nk+1) + dst + 1]);
    const int2* ep = epack + (size_t)r*Ek;
    const char* xb = (const char*)(xh + (size_t)b*Nk*64);

    float acc = 0.f;
    int e = o0;
    for(; e + 4 <= o1; e += 4){
        int2 p0 = ep[e+0];
        int2 p1 = ep[e+1];
        int2 p2 = ep[e+2];
        int2 p3 = ep[e+3];
        const u16* r0 = (const u16*)(xb + p0.x);
        const u16* r1 = (const u16*)(xb + p1.x);
        const u16* r2 = (const u16*)(xb + p2.x);
        const u16* r3 = (const u16*)(xb + p3.x);
        float v0 = bf2f(r0[lane]);
        float v1 = bf2f(r1[lane]);
        float v2 = bf2f(r2[lane]);
        float v3 = bf2f(r3[lane]);
        acc += __int_as_float(p0.y) * v0;
        acc += __int_as_float(p1.y) * v1;
        acc += __int_as_float(p2.y) * v2;
        acc += __int_as_float(p3.y) * v3;
    }
    for(; e < o1; ++e){
        int2 p = ep[e];
        const u16* rr = (const u16*)(xb + p.x);
        acc += __int_as_float(p.y) * bf2f(rr[lane]);
    }
    aggh[(((size_t)r*Bk + b)*Nk + dst)*64 + lane] = f2bf(acc);
}

// ---------------------------------------------------------------------------
// MFMA projection + LN + ReLU. Wave = 16 nodes x 64 feats.
// A-frag: A[m=lane&15][k=quad*8+j], 16B contiguous per lane, direct global.
// B-frag: pre-transposed wt_hi/wt_lo (k_wprep). W = hi + lo (fp32-accurate).
// C/D: col=lane&15, row=quad*4+reg. LN via xor-shuffle within 16-lane groups.
// ---------------------------------------------------------------------------
__global__ __launch_bounds__(256) void k_proj_mfma(u16* __restrict__ xh,
        const u16* __restrict__ aggh,
        const u16* __restrict__ wt_hi, const u16* __restrict__ wt_lo,
        const float* __restrict__ ln_g, const float* __restrict__ ln_b, int l){
    int lane = threadIdx.x & 63;
    int wq   = threadIdx.x >> 6;
    int b    = blockIdx.y;
    int n0   = blockIdx.x*64 + wq*16;     // 16 nodes for this wave
    int mrow = lane & 15;
    int kq   = lane >> 4;
    int node_a = n0 + mrow;
    if(node_a >= Nk) node_a = Nk - 1;     // clamp; invalid rows never stored

    f32x4 acc[4];
    #pragma unroll
    for(int jt = 0; jt < 4; ++jt) acc[jt] = (f32x4){0.f,0.f,0.f,0.f};

    const u16* wl_hi = wt_hi + (size_t)l*16384;
    const u16* wl_lo = wt_lo + (size_t)l*16384;

    #pragma unroll
    for(int mt = 0; mt < 4; ++mt){
        const u16* arow = (mt == 0)
            ? xh   + ((size_t)b*Nk + node_a)*64
            : aggh + (((size_t)(mt-1)*Bk + b)*Nk + node_a)*64;
        #pragma unroll
        for(int kc = 0; kc < 2; ++kc){
            bf16x8 afrag = *(const bf16x8*)(arow + kc*32 + kq*8);
            #pragma unroll
            for(int jt = 0; jt < 4; ++jt){
                size_t wi = ((size_t)((mt*2 + kc)*4 + jt)*64 + lane)*8;
                bf16x8 bh = *(const bf16x8*)(wl_hi + wi);
                bf16x8 bl = *(const bf16x8*)(wl_lo + wi);
                acc[jt] = __builtin_amdgcn_mfma_f32_16x16x32_bf16(afrag, bh, acc[jt], 0, 0, 0);
                acc[jt] = __builtin_amdgcn_mfma_f32_16x16x32_bf16(afrag, bl, acc[jt], 0, 0, 0);
            }
        }
    }

    float gv[4], bv[4];
    #pragma unroll
    for(int jt = 0; jt < 4; ++jt){
        int f = jt*16 + mrow;
        gv[jt] = ln_g[l*64 + f];
        bv[jt] = ln_b[l*64 + f];
    }

    u16* xdst = xh + (size_t)b*Nk*64;
    #pragma unroll
    for(int v = 0; v < 4; ++v){
        float s1 = acc[0][v] + acc[1][v] + acc[2][v] + acc[3][v];
        float s2 = acc[0][v]*acc[0][v] + acc[1][v]*acc[1][v]
                 + acc[2][v]*acc[2][v] + acc[3][v]*acc[3][v];
        #pragma unroll
        for(int off = 1; off <= 8; off <<= 1){
            s1 += __shfl_xor(s1, off);
            s2 += __shfl_xor(s2, off);
        }
        float mu  = s1 * 0.015625f;
        float var = s2 * 0.015625f - mu*mu;
        float rstd = rsqrtf(var + 1e-3f);
        int node = n0 + kq*4 + v;
        if(node < Nk){
            #pragma unroll
            for(int jt = 0; jt < 4; ++jt){
                float o = (acc[jt][v] - mu) * rstd * gv[jt] + bv[jt];
                xdst[(size_t)node*64 + jt*16 + mrow] = f2bf(fmaxf(o, 0.f));
            }
        }
    }
}

// ---------------------------------------------------------------------------
// out[b,n] = dot(x[b,n,:], W_out) + b_out
// ---------------------------------------------------------------------------
__global__ void k_final(const u16* __restrict__ xh, const float* __restrict__ W_out,
                        const float* __restrict__ b_out, float* __restrict__ out){
    int wid = (blockIdx.x*256 + threadIdx.x) >> 6;
    int lane = threadIdx.x & 63;
    int nwaves = gridDim.x * 4;
    float w = W_out[lane];
    float bo = b_out[0];
    for(int node = wid; node < Bk*Nk; node += nwaves){
        float v = bf2f(xh[(size_t)node*64 + lane]) * w;
        #pragma unroll
        for(int off = 32; off; off >>= 1) v += __shfl_xor(v, off);
        if(lane == 0) out[node] = v + bo;
    }
}

// ---------------------------------------------------------------------------
extern "C" void kernel_launch(void* const* d_in, const int* in_sizes, int n_in,
                              void* d_out, int out_size, void* d_ws, size_t ws_size,
                              hipStream_t stream){
    const float* ctl        = (const float*)d_in[0];
    const float* dt         = (const float*)d_in[1];
    const float* drug_fp    = (const float*)d_in[2];
    const float* edge_w     = (const float*)d_in[3];
    const int*   cell_idx   = (const int*)  d_in[4];
    const int*   edge_index = (const int*)  d_in[5];
    const float* W_se       = (const float*)d_in[6];
    const float* b_se       = (const float*)d_in[7];
    const float* cell_emb   = (const float*)d_in[8];
    const float* W_f1       = (const float*)d_in[9];
    const float* b_f1       = (const float*)d_in[10];
    const float* W_f2       = (const float*)d_in[11];
    const float* b_f2       = (const float*)d_in[12];
    const float* Wself      = (const float*)d_in[13];
    const float* Wrel       = (const float*)d_in[14];
    const float* ln_g       = (const float*)d_in[15];
    const float* ln_b       = (const float*)d_in[16];
    const float* W_out      = (const float*)d_in[17];
    const float* b_out      = (const float*)d_in[18];
    float* out = (float*)d_out;

    char* p = (char*)d_ws;
    auto alloc = [&](size_t bytes)->char*{
        char* r = p; p += (bytes + 255) & ~(size_t)255; return r;
    };
    int*   deg    = (int*)  alloc((size_t)Rk*Nk*4);
    int*   cursor = (int*)  alloc((size_t)Rk*Nk*4);
    int*   offs   = (int*)  alloc((size_t)Rk*(Nk+1)*4);
    int2*  epack  = (int2*) alloc((size_t)Rk*Ek*8);
    float* hid    = (float*)alloc((size_t)Bk*64*4);
    float* g1p    = (float*)alloc((size_t)Bk*64*4);
    float* beta   = (float*)alloc((size_t)Bk*64*4);
    u16*   xh     = (u16*)  alloc((size_t)Bk*Nk*64*2);
    u16*   aggh   = (u16*)  alloc((size_t)3*Bk*Nk*64*2);
    u16*   wt_hi  = (u16*)  alloc((size_t)Lk*16384*2);
    u16*   wt_lo  = (u16*)  alloc((size_t)Lk*16384*2);

    // CSR build (edge structure is layer-invariant; rebuilt every launch)
    k_zero<<<(Rk*Nk + 255)/256, 256, 0, stream>>>(deg, Rk*Nk);
    k_count<<<(Rk*Ek + 255)/256, 256, 0, stream>>>(edge_index, deg);
    k_scan<<<Rk, 1024, 0, stream>>>(deg, offs, cursor);
    k_fill<<<(Rk*Ek + 255)/256, 256, 0, stream>>>(edge_index, edge_w, cursor, epack);

    // weight prep for MFMA projection (all layers at once)
    k_wprep<<<(Lk*4*2*4*64*8 + 255)/256, 256, 0, stream>>>(Wself, Wrel, wt_hi, wt_lo);

    // FiLM
    k_film1<<<Bk*64, 256, 0, stream>>>(drug_fp, W_f1, b_f1, hid);
    k_film2<<<Bk, 128, 0, stream>>>(hid, W_f2, b_f2, g1p, beta);

    // x0
    k_init<<<2048, 256, 0, stream>>>(ctl, dt, cell_idx, W_se, b_se, cell_emb, g1p, beta, xh);

    // layers
    for(int l = 0; l < Lk; ++l){
        k_agg<<<8*7500, 256, 0, stream>>>(xh, offs, epack, aggh);
        k_proj_mfma<<<dim3((Nk + 63)/64, Bk), 256, 0, stream>>>(
            xh, aggh, wt_hi, wt_lo, ln_g, ln_b, l);
    }

    // readout
    k_final<<<512, 256, 0, stream>>>(xh, W_out, b_out, out);
}

// Round 7
// 497.748 us; speedup vs baseline: 1.6891x; 1.6891x over previous
//
#include <hip/hip_runtime.h>
#include <hip/hip_bf16.h>
#include <math.h>

#define Bk 8
#define Nk 10000
#define Hk 64
#define Lk 4
#define Rk 3
#define Ek 200000
#define FPk 2048

typedef unsigned short u16;
typedef unsigned int   u32;
typedef __attribute__((ext_vector_type(8))) short bf16x8;
typedef __attribute__((ext_vector_type(4))) float f32x4;

__device__ __forceinline__ float bf2f(u16 u){
    union{u32 i; float f;} v; v.i = (u32)u << 16; return v.f;
}
__device__ __forceinline__ float bf2f_lo(u32 u){
    union{u32 i; float f;} v; v.i = u << 16; return v.f;
}
__device__ __forceinline__ float bf2f_hi(u32 u){
    union{u32 i; float f;} v; v.i = u & 0xffff0000u; return v.f;
}
__device__ __forceinline__ u16 f2bf(float f){      // round-to-nearest-even
    union{u32 i; float f;} v; v.f = f;
    u32 r = v.i + 0x7fffu + ((v.i >> 16) & 1u);
    return (u16)(r >> 16);
}

// ---------------------------------------------------------------------------
// CSR build
// ---------------------------------------------------------------------------
__global__ void k_zero(int* p, int n){
    int i = blockIdx.x*256 + threadIdx.x;
    if(i < n) p[i] = 0;
}

__global__ void k_count(const int* edge_index, int* deg){
    int idx = blockIdx.x*256 + threadIdx.x;
    if(idx >= Rk*Ek) return;
    int r = idx / Ek, e = idx % Ek;
    int dst = edge_index[r*2*Ek + Ek + e];
    atomicAdd(&deg[r*Nk + dst], 1);
}

__global__ void k_scan(const int* deg, int* offs, int* cursor){
    int r = blockIdx.x;
    __shared__ int s[1024];
    __shared__ int carry;
    if(threadIdx.x == 0) carry = 0;
    __syncthreads();
    for(int base = 0; base < Nk; base += 1024){
        int i = base + threadIdx.x;
        int v = (i < Nk) ? deg[r*Nk + i] : 0;
        s[threadIdx.x] = v;
        __syncthreads();
        for(int d = 1; d < 1024; d <<= 1){
            int t = (threadIdx.x >= d) ? s[threadIdx.x - d] : 0;
            __syncthreads();
            s[threadIdx.x] += t;
            __syncthreads();
        }
        int incl = s[threadIdx.x];
        int excl = carry + incl - v;
        if(i < Nk){ offs[r*(Nk+1)+i] = excl; cursor[r*Nk+i] = excl; }
        __syncthreads();
        if(threadIdx.x == 1023) carry += s[1023];
        __syncthreads();
    }
    if(threadIdx.x == 0) offs[r*(Nk+1)+Nk] = carry;
}

// pack each edge as {src*128 (byte offset into a 64-feat bf16 row), w bits}
__global__ void k_fill(const int* edge_index, const float* edge_weight,
                       int* cursor, int2* epack){
    int idx = blockIdx.x*256 + threadIdx.x;
    if(idx >= Rk*Ek) return;
    int r = idx / Ek, e = idx % Ek;
    int src = edge_index[r*2*Ek + e];
    int dst = edge_index[r*2*Ek + Ek + e];
    int pos = atomicAdd(&cursor[r*Nk + dst], 1);
    epack[(size_t)r*Ek + pos] = make_int2(src << 7, __float_as_int(edge_weight[r*Ek + e]));
}

// ---------------------------------------------------------------------------
// Weight prep: W -> MFMA B-operand layout, split hi/lo bf16 (fp32-accurate).
// ---------------------------------------------------------------------------
__global__ void k_wprep(const float* __restrict__ Wself, const float* __restrict__ Wrel,
                        u16* __restrict__ wt_hi, u16* __restrict__ wt_lo){
    int idx = blockIdx.x*256 + threadIdx.x;
    if(idx >= Lk*4*2*4*64*8) return;
    int j    = idx & 7;
    int lane = (idx >> 3) & 63;
    int jt   = (idx >> 9) & 3;
    int kc   = (idx >> 11) & 1;
    int mt   = (idx >> 12) & 3;
    int l    = idx >> 14;
    int k    = kc*32 + (lane >> 4)*8 + j;
    int col  = jt*16 + (lane & 15);
    float w = (mt == 0) ? Wself[(l*64 + k)*64 + col]
                        : Wrel[((l*3 + (mt-1))*64 + k)*64 + col];
    u16 hi = f2bf(w);
    u16 lo = f2bf(w - bf2f(hi));
    wt_hi[idx] = hi;
    wt_lo[idx] = lo;
}

// ---------------------------------------------------------------------------
// FiLM
// ---------------------------------------------------------------------------
__global__ void k_film1(const float* fp, const float* W1, const float* b1, float* hid){
    int b = blockIdx.x >> 6, h = blockIdx.x & 63;
    const float* fpb = fp + b*FPk;
    float acc = 0.f;
    for(int k = threadIdx.x; k < FPk; k += 256)
        acc += fpb[k] * W1[k*64 + h];
    __shared__ float red[256];
    red[threadIdx.x] = acc;
    __syncthreads();
    for(int s = 128; s >= 1; s >>= 1){
        if(threadIdx.x < s) red[threadIdx.x] += red[threadIdx.x + s];
        __syncthreads();
    }
    if(threadIdx.x == 0) hid[b*64 + h] = fmaxf(red[0] + b1[h], 0.f);
}

__global__ void k_film2(const float* hid, const float* W2, const float* b2,
                        float* g1p, float* beta){
    int b = blockIdx.x, j = threadIdx.x;   // 128 threads
    float acc = b2[j];
    for(int k = 0; k < 64; ++k)
        acc += hid[b*64 + k] * W2[k*128 + j];
    if(j < 64) g1p[b*64 + j] = 1.f + tanhf(acc);
    else       beta[b*64 + j - 64] = acc;
}

// ---------------------------------------------------------------------------
// x0 (bf16)
// ---------------------------------------------------------------------------
__global__ void k_init(const float* ctl, const float* dt, const int* cell_idx,
                       const float* W_se, const float* b_se, const float* cell_emb,
                       const float* g1p, const float* beta, u16* xh){
    const size_t total = (size_t)Bk*Nk*64;
    for(size_t i = (size_t)blockIdx.x*256 + threadIdx.x; i < total; i += (size_t)gridDim.x*256){
        int h = (int)(i & 63);
        size_t bn = i >> 6;
        int b = (int)(bn / Nk);
        float w = W_se[h], bs = b_se[h];
        float v = fmaxf(ctl[bn]*w + bs, 0.f) + fmaxf(dt[bn]*w + bs, 0.f)
                + cell_emb[cell_idx[b]*64 + h];
        xh[i] = f2bf(v * g1p[b*64 + h] + beta[b*64 + h]);
    }
}

// ---------------------------------------------------------------------------
// agg (bf16): wave = one (r,dst) x 2 batches (lane>>5) x 32 feat-pairs (lane&31).
// Records: cooperative 64-wide coalesced chunk load -> per-wave LDS stash ->
// per-edge same-address ds_read_b64 broadcast (conflict-free, imm offsets).
// One global_load_dword gather serves 2 feats; bpair=blockIdx&3 keeps each
// XCD on a 2.56MB slice (L2-resident).
// ---------------------------------------------------------------------------
__global__ __launch_bounds__(256) void k_agg(const u16* __restrict__ xh,
                      const int* __restrict__ offs, const int2* __restrict__ epack,
                      u16* __restrict__ aggh){
    __shared__ int2 stash[4][64];
    int bpair = blockIdx.x & 3;
    int grp   = blockIdx.x >> 2;                   // 0..7499
    int wq    = threadIdx.x >> 6;
    int wid   = grp*4 + wq;                        // 0..29999 = (r,dst)
    int lane  = threadIdx.x & 63;
    int fg    = lane & 31;                         // feature pair (2 bf16)
    int bl    = lane >> 5;                         // local batch 0/1
    int b     = bpair*2 + bl;
    int r = wid / Nk, dst = wid % Nk;
    int o0 = offs[r*(Nk+1) + dst], o1 = offs[r*(Nk+1) + dst + 1];
    const int2* ep = epack + (size_t)r*Ek;
    const char* xb = (const char*)xh + (size_t)b*Nk*128 + fg*4;

    float acc0a = 0.f, acc1a = 0.f, acc0b = 0.f, acc1b = 0.f;
    int2* st = stash[wq];
    for(int base = o0; base < o1; base += 64){
        int j = base + lane;
        if(j < o1) st[lane] = ep[j];
        int cnt = o1 - base; if(cnt > 64) cnt = 64;
        int t = 0;
        for(; t + 4 <= cnt; t += 4){
            int2 p0 = st[t+0];
            int2 p1 = st[t+1];
            int2 p2 = st[t+2];
            int2 p3 = st[t+3];
            u32 u0 = *(const u32*)(xb + p0.x);
            u32 u1 = *(const u32*)(xb + p1.x);
            u32 u2 = *(const u32*)(xb + p2.x);
            u32 u3 = *(const u32*)(xb + p3.x);
            float w0 = __int_as_float(p0.y), w1 = __int_as_float(p1.y);
            float w2 = __int_as_float(p2.y), w3 = __int_as_float(p3.y);
            acc0a += w0 * bf2f_lo(u0); acc1a += w0 * bf2f_hi(u0);
            acc0b += w1 * bf2f_lo(u1); acc1b += w1 * bf2f_hi(u1);
            acc0a += w2 * bf2f_lo(u2); acc1a += w2 * bf2f_hi(u2);
            acc0b += w3 * bf2f_lo(u3); acc1b += w3 * bf2f_hi(u3);
        }
        for(; t < cnt; ++t){
            int2 p = st[t];
            u32 u = *(const u32*)(xb + p.x);
            float w = __int_as_float(p.y);
            acc0a += w * bf2f_lo(u); acc1a += w * bf2f_hi(u);
        }
    }
    float a0 = acc0a + acc0b, a1 = acc1a + acc1b;
    u32 packed = (u32)f2bf(a0) | ((u32)f2bf(a1) << 16);
    ((u32*)aggh)[(((size_t)r*Bk + b)*Nk + dst)*32 + fg] = packed;
}

// ---------------------------------------------------------------------------
// MFMA projection + LN + ReLU. Wave = 16 nodes x 64 feats.
// A-frag: A[m=lane&15][k=quad*8+j], 16B contiguous per lane, direct global.
// B-frag: pre-transposed wt_hi/wt_lo (k_wprep). W = hi + lo (fp32-accurate).
// C/D: col=lane&15, row=quad*4+reg. LN via xor-shuffle within 16-lane groups.
// ---------------------------------------------------------------------------
__global__ __launch_bounds__(256) void k_proj_mfma(u16* __restrict__ xh,
        const u16* __restrict__ aggh,
        const u16* __restrict__ wt_hi, const u16* __restrict__ wt_lo,
        const float* __restrict__ ln_g, const float* __restrict__ ln_b, int l){
    int lane = threadIdx.x & 63;
    int wq   = threadIdx.x >> 6;
    int b    = blockIdx.y;
    int n0   = blockIdx.x*64 + wq*16;     // 16 nodes for this wave
    int mrow = lane & 15;
    int kq   = lane >> 4;
    int node_a = n0 + mrow;
    if(node_a >= Nk) node_a = Nk - 1;     // clamp; invalid rows never stored

    f32x4 acc[4];
    #pragma unroll
    for(int jt = 0; jt < 4; ++jt) acc[jt] = (f32x4){0.f,0.f,0.f,0.f};

    const u16* wl_hi = wt_hi + (size_t)l*16384;
    const u16* wl_lo = wt_lo + (size_t)l*16384;

    #pragma unroll
    for(int mt = 0; mt < 4; ++mt){
        const u16* arow = (mt == 0)
            ? xh   + ((size_t)b*Nk + node_a)*64
            : aggh + (((size_t)(mt-1)*Bk + b)*Nk + node_a)*64;
        #pragma unroll
        for(int kc = 0; kc < 2; ++kc){
            bf16x8 afrag = *(const bf16x8*)(arow + kc*32 + kq*8);
            #pragma unroll
            for(int jt = 0; jt < 4; ++jt){
                size_t wi = ((size_t)((mt*2 + kc)*4 + jt)*64 + lane)*8;
                bf16x8 bh = *(const bf16x8*)(wl_hi + wi);
                bf16x8 bl = *(const bf16x8*)(wl_lo + wi);
                acc[jt] = __builtin_amdgcn_mfma_f32_16x16x32_bf16(afrag, bh, acc[jt], 0, 0, 0);
                acc[jt] = __builtin_amdgcn_mfma_f32_16x16x32_bf16(afrag, bl, acc[jt], 0, 0, 0);
            }
        }
    }

    float gv[4], bv[4];
    #pragma unroll
    for(int jt = 0; jt < 4; ++jt){
        int f = jt*16 + mrow;
        gv[jt] = ln_g[l*64 + f];
        bv[jt] = ln_b[l*64 + f];
    }

    u16* xdst = xh + (size_t)b*Nk*64;
    #pragma unroll
    for(int v = 0; v < 4; ++v){
        float s1 = acc[0][v] + acc[1][v] + acc[2][v] + acc[3][v];
        float s2 = acc[0][v]*acc[0][v] + acc[1][v]*acc[1][v]
                 + acc[2][v]*acc[2][v] + acc[3][v]*acc[3][v];
        #pragma unroll
        for(int off = 1; off <= 8; off <<= 1){
            s1 += __shfl_xor(s1, off);
            s2 += __shfl_xor(s2, off);
        }
        float mu  = s1 * 0.015625f;
        float var = s2 * 0.015625f - mu*mu;
        float rstd = rsqrtf(var + 1e-3f);
        int node = n0 + kq*4 + v;
        if(node < Nk){
            #pragma unroll
            for(int jt = 0; jt < 4; ++jt){
                float o = (acc[jt][v] - mu) * rstd * gv[jt] + bv[jt];
                xdst[(size_t)node*64 + jt*16 + mrow] = f2bf(fmaxf(o, 0.f));
            }
        }
    }
}

// ---------------------------------------------------------------------------
// out[b,n] = dot(x[b,n,:], W_out) + b_out
// ---------------------------------------------------------------------------
__global__ void k_final(const u16* __restrict__ xh, const float* __restrict__ W_out,
                        const float* __restrict__ b_out, float* __restrict__ out){
    int wid = (blockIdx.x*256 + threadIdx.x) >> 6;
    int lane = threadIdx.x & 63;
    int nwaves = gridDim.x * 4;
    float w = W_out[lane];
    float bo = b_out[0];
    for(int node = wid; node < Bk*Nk; node += nwaves){
        float v = bf2f(xh[(size_t)node*64 + lane]) * w;
        #pragma unroll
        for(int off = 32; off; off >>= 1) v += __shfl_xor(v, off);
        if(lane == 0) out[node] = v + bo;
    }
}

// ---------------------------------------------------------------------------
extern "C" void kernel_launch(void* const* d_in, const int* in_sizes, int n_in,
                              void* d_out, int out_size, void* d_ws, size_t ws_size,
                              hipStream_t stream){
    const float* ctl        = (const float*)d_in[0];
    const float* dt         = (const float*)d_in[1];
    const float* drug_fp    = (const float*)d_in[2];
    const float* edge_w     = (const float*)d_in[3];
    const int*   cell_idx   = (const int*)  d_in[4];
    const int*   edge_index = (const int*)  d_in[5];
    const float* W_se       = (const float*)d_in[6];
    const float* b_se       = (const float*)d_in[7];
    const float* cell_emb   = (const float*)d_in[8];
    const float* W_f1       = (const float*)d_in[9];
    const float* b_f1       = (const float*)d_in[10];
    const float* W_f2       = (const float*)d_in[11];
    const float* b_f2       = (const float*)d_in[12];
    const float* Wself      = (const float*)d_in[13];
    const float* Wrel       = (const float*)d_in[14];
    const float* ln_g       = (const float*)d_in[15];
    const float* ln_b       = (const float*)d_in[16];
    const float* W_out      = (const float*)d_in[17];
    const float* b_out      = (const float*)d_in[18];
    float* out = (float*)d_out;

    char* p = (char*)d_ws;
    auto alloc = [&](size_t bytes)->char*{
        char* r = p; p += (bytes + 255) & ~(size_t)255; return r;
    };
    int*   deg    = (int*)  alloc((size_t)Rk*Nk*4);
    int*   cursor = (int*)  alloc((size_t)Rk*Nk*4);
    int*   offs   = (int*)  alloc((size_t)Rk*(Nk+1)*4);
    int2*  epack  = (int2*) alloc((size_t)Rk*Ek*8);
    float* hid    = (float*)alloc((size_t)Bk*64*4);
    float* g1p    = (float*)alloc((size_t)Bk*64*4);
    float* beta   = (float*)alloc((size_t)Bk*64*4);
    u16*   xh     = (u16*)  alloc((size_t)Bk*Nk*64*2);
    u16*   aggh   = (u16*)  alloc((size_t)3*Bk*Nk*64*2);
    u16*   wt_hi  = (u16*)  alloc((size_t)Lk*16384*2);
    u16*   wt_lo  = (u16*)  alloc((size_t)Lk*16384*2);

    // CSR build (edge structure is layer-invariant; rebuilt every launch)
    k_zero<<<(Rk*Nk + 255)/256, 256, 0, stream>>>(deg, Rk*Nk);
    k_count<<<(Rk*Ek + 255)/256, 256, 0, stream>>>(edge_index, deg);
    k_scan<<<Rk, 1024, 0, stream>>>(deg, offs, cursor);
    k_fill<<<(Rk*Ek + 255)/256, 256, 0, stream>>>(edge_index, edge_w, cursor, epack);

    // weight prep for MFMA projection (all layers at once)
    k_wprep<<<(Lk*4*2*4*64*8 + 255)/256, 256, 0, stream>>>(Wself, Wrel, wt_hi, wt_lo);

    // FiLM
    k_film1<<<Bk*64, 256, 0, stream>>>(drug_fp, W_f1, b_f1, hid);
    k_film2<<<Bk, 128, 0, stream>>>(hid, W_f2, b_f2, g1p, beta);

    // x0
    k_init<<<2048, 256, 0, stream>>>(ctl, dt, cell_idx, W_se, b_se, cell_emb, g1p, beta, xh);

    // layers
    for(int l = 0; l < Lk; ++l){
        // 4 bpairs x 7500 groups x 4 waves; bpair=blockIdx&3 -> per-XCD 2.56MB slice
        k_agg<<<4*7500, 256, 0, stream>>>(xh, offs, epack, aggh);
        k_proj_mfma<<<dim3((Nk + 63)/64, Bk), 256, 0, stream>>>(
            xh, aggh, wt_hi, wt_lo, ln_g, ln_b, l);
    }

    // readout
    k_final<<<512, 256, 0, stream>>>(xh, W_out, b_out, out);
}

// Round 8
// 453.858 us; speedup vs baseline: 1.8524x; 1.0967x over previous
//
#include <hip/hip_runtime.h>
#include <hip/hip_bf16.h>
#include <math.h>

#define Bk 8
#define Nk 10000
#define Hk 64
#define Lk 4
#define Rk 3
#define Ek 200000
#define FPk 2048

typedef unsigned short u16;
typedef unsigned int   u32;
typedef __attribute__((ext_vector_type(8))) short bf16x8;
typedef __attribute__((ext_vector_type(4))) float f32x4;

__device__ __forceinline__ float bf2f(u16 u){
    union{u32 i; float f;} v; v.i = (u32)u << 16; return v.f;
}
__device__ __forceinline__ float bf2f_lo(u32 u){
    union{u32 i; float f;} v; v.i = u << 16; return v.f;
}
__device__ __forceinline__ float bf2f_hi(u32 u){
    union{u32 i; float f;} v; v.i = u & 0xffff0000u; return v.f;
}
__device__ __forceinline__ u16 f2bf(float f){      // round-to-nearest-even
    union{u32 i; float f;} v; v.f = f;
    u32 r = v.i + 0x7fffu + ((v.i >> 16) & 1u);
    return (u16)(r >> 16);
}

// ---------------------------------------------------------------------------
// CSR build
// ---------------------------------------------------------------------------
__global__ void k_zero(int* p, int n){
    int i = blockIdx.x*256 + threadIdx.x;
    if(i < n) p[i] = 0;
}

__global__ void k_count(const int* edge_index, int* deg){
    int idx = blockIdx.x*256 + threadIdx.x;
    if(idx >= Rk*Ek) return;
    int r = idx / Ek, e = idx % Ek;
    int dst = edge_index[r*2*Ek + Ek + e];
    atomicAdd(&deg[r*Nk + dst], 1);
}

__global__ void k_scan(const int* deg, int* offs, int* cursor){
    int r = blockIdx.x;
    __shared__ int s[1024];
    __shared__ int carry;
    if(threadIdx.x == 0) carry = 0;
    __syncthreads();
    for(int base = 0; base < Nk; base += 1024){
        int i = base + threadIdx.x;
        int v = (i < Nk) ? deg[r*Nk + i] : 0;
        s[threadIdx.x] = v;
        __syncthreads();
        for(int d = 1; d < 1024; d <<= 1){
            int t = (threadIdx.x >= d) ? s[threadIdx.x - d] : 0;
            __syncthreads();
            s[threadIdx.x] += t;
            __syncthreads();
        }
        int incl = s[threadIdx.x];
        int excl = carry + incl - v;
        if(i < Nk){ offs[r*(Nk+1)+i] = excl; cursor[r*Nk+i] = excl; }
        __syncthreads();
        if(threadIdx.x == 1023) carry += s[1023];
        __syncthreads();
    }
    if(threadIdx.x == 0) offs[r*(Nk+1)+Nk] = carry;
}

// pack each edge as {src*128 (byte offset into a 64-feat bf16 row), w bits}
__global__ void k_fill(const int* edge_index, const float* edge_weight,
                       int* cursor, int2* epack){
    int idx = blockIdx.x*256 + threadIdx.x;
    if(idx >= Rk*Ek) return;
    int r = idx / Ek, e = idx % Ek;
    int src = edge_index[r*2*Ek + e];
    int dst = edge_index[r*2*Ek + Ek + e];
    int pos = atomicAdd(&cursor[r*Nk + dst], 1);
    epack[(size_t)r*Ek + pos] = make_int2(src << 7, __float_as_int(edge_weight[r*Ek + e]));
}

// ---------------------------------------------------------------------------
// Weight prep: W -> MFMA B-operand layout, split hi/lo bf16 (fp32-accurate).
// ---------------------------------------------------------------------------
__global__ void k_wprep(const float* __restrict__ Wself, const float* __restrict__ Wrel,
                        u16* __restrict__ wt_hi, u16* __restrict__ wt_lo){
    int idx = blockIdx.x*256 + threadIdx.x;
    if(idx >= Lk*4*2*4*64*8) return;
    int j    = idx & 7;
    int lane = (idx >> 3) & 63;
    int jt   = (idx >> 9) & 3;
    int kc   = (idx >> 11) & 1;
    int mt   = (idx >> 12) & 3;
    int l    = idx >> 14;
    int k    = kc*32 + (lane >> 4)*8 + j;
    int col  = jt*16 + (lane & 15);
    float w = (mt == 0) ? Wself[(l*64 + k)*64 + col]
                        : Wrel[((l*3 + (mt-1))*64 + k)*64 + col];
    u16 hi = f2bf(w);
    u16 lo = f2bf(w - bf2f(hi));
    wt_hi[idx] = hi;
    wt_lo[idx] = lo;
}

// ---------------------------------------------------------------------------
// FiLM
// ---------------------------------------------------------------------------
__global__ void k_film1(const float* fp, const float* W1, const float* b1, float* hid){
    int b = blockIdx.x >> 6, h = blockIdx.x & 63;
    const float* fpb = fp + b*FPk;
    float acc = 0.f;
    for(int k = threadIdx.x; k < FPk; k += 256)
        acc += fpb[k] * W1[k*64 + h];
    __shared__ float red[256];
    red[threadIdx.x] = acc;
    __syncthreads();
    for(int s = 128; s >= 1; s >>= 1){
        if(threadIdx.x < s) red[threadIdx.x] += red[threadIdx.x + s];
        __syncthreads();
    }
    if(threadIdx.x == 0) hid[b*64 + h] = fmaxf(red[0] + b1[h], 0.f);
}

__global__ void k_film2(const float* hid, const float* W2, const float* b2,
                        float* g1p, float* beta){
    int b = blockIdx.x, j = threadIdx.x;   // 128 threads
    float acc = b2[j];
    for(int k = 0; k < 64; ++k)
        acc += hid[b*64 + k] * W2[k*128 + j];
    if(j < 64) g1p[b*64 + j] = 1.f + tanhf(acc);
    else       beta[b*64 + j - 64] = acc;
}

// ---------------------------------------------------------------------------
// x0 (bf16)
// ---------------------------------------------------------------------------
__global__ void k_init(const float* ctl, const float* dt, const int* cell_idx,
                       const float* W_se, const float* b_se, const float* cell_emb,
                       const float* g1p, const float* beta, u16* xh){
    const size_t total = (size_t)Bk*Nk*64;
    for(size_t i = (size_t)blockIdx.x*256 + threadIdx.x; i < total; i += (size_t)gridDim.x*256){
        int h = (int)(i & 63);
        size_t bn = i >> 6;
        int b = (int)(bn / Nk);
        float w = W_se[h], bs = b_se[h];
        float v = fmaxf(ctl[bn]*w + bs, 0.f) + fmaxf(dt[bn]*w + bs, 0.f)
                + cell_emb[cell_idx[b]*64 + h];
        xh[i] = f2bf(v * g1p[b*64 + h] + beta[b*64 + h]);
    }
}

// ---------------------------------------------------------------------------
// agg (bf16): wave = one (r,dst) x 4 batches (lane>>4) x 16 feat-quads (lane&15).
// Records: cooperative coalesced chunk -> per-wave LDS stash -> b128 broadcast
// reads (2 records/read). One global_load_dwordx2 gather serves 4 feats.
// quad=blockIdx&1 (XCD parity) -> per-XCD gather slice = 4 batches = 5.12MB.
// ---------------------------------------------------------------------------
__global__ __launch_bounds__(256) void k_agg(const u16* __restrict__ xh,
                      const int* __restrict__ offs, const int2* __restrict__ epack,
                      u16* __restrict__ aggh){
    __shared__ int2 stash[4][64];
    int quad  = blockIdx.x & 1;                    // batch quad 0/1
    int grp   = blockIdx.x >> 1;                   // 0..7499
    int wq    = threadIdx.x >> 6;
    int wid   = grp*4 + wq;                        // 0..29999 = (r,dst)
    int lane  = threadIdx.x & 63;
    int fg    = lane & 15;                         // feat quad: feats fg*4..+3
    int bl    = lane >> 4;                         // local batch 0..3
    int b     = quad*4 + bl;
    int r = wid / Nk, dst = wid % Nk;
    int o0 = offs[r*(Nk+1) + dst], o1 = offs[r*(Nk+1) + dst + 1];
    const int2* ep = epack + (size_t)r*Ek;
    const char* xb = (const char*)xh + (size_t)b*Nk*128 + fg*8;

    float a0=0.f,a1=0.f,a2=0.f,a3=0.f;   // chain A
    float c0=0.f,c1=0.f,c2=0.f,c3=0.f;   // chain C
    int2* st = stash[wq];
    for(int base = o0; base < o1; base += 64){
        int j = base + lane;
        if(j < o1) st[lane] = ep[j];
        int cnt = min(o1 - base, 64);
        int t = 0;
        for(; t + 4 <= cnt; t += 4){
            int4 q01 = *(const int4*)&st[t];       // records t, t+1
            int4 q23 = *(const int4*)&st[t+2];     // records t+2, t+3
            uint2 u0 = *(const uint2*)(xb + q01.x);
            uint2 u1 = *(const uint2*)(xb + q01.z);
            uint2 u2 = *(const uint2*)(xb + q23.x);
            uint2 u3 = *(const uint2*)(xb + q23.z);
            float w0 = __int_as_float(q01.y), w1 = __int_as_float(q01.w);
            float w2 = __int_as_float(q23.y), w3 = __int_as_float(q23.w);
            a0 += w0*bf2f_lo(u0.x); a1 += w0*bf2f_hi(u0.x);
            a2 += w0*bf2f_lo(u0.y); a3 += w0*bf2f_hi(u0.y);
            c0 += w1*bf2f_lo(u1.x); c1 += w1*bf2f_hi(u1.x);
            c2 += w1*bf2f_lo(u1.y); c3 += w1*bf2f_hi(u1.y);
            a0 += w2*bf2f_lo(u2.x); a1 += w2*bf2f_hi(u2.x);
            a2 += w2*bf2f_lo(u2.y); a3 += w2*bf2f_hi(u2.y);
            c0 += w3*bf2f_lo(u3.x); c1 += w3*bf2f_hi(u3.x);
            c2 += w3*bf2f_lo(u3.y); c3 += w3*bf2f_hi(u3.y);
        }
        for(; t < cnt; ++t){
            int2 p = st[t];
            uint2 u = *(const uint2*)(xb + p.x);
            float w = __int_as_float(p.y);
            a0 += w*bf2f_lo(u.x); a1 += w*bf2f_hi(u.x);
            a2 += w*bf2f_lo(u.y); a3 += w*bf2f_hi(u.y);
        }
    }
    a0 += c0; a1 += c1; a2 += c2; a3 += c3;
    u32 plo = (u32)f2bf(a0) | ((u32)f2bf(a1) << 16);
    u32 phi = (u32)f2bf(a2) | ((u32)f2bf(a3) << 16);
    ((uint2*)aggh)[(((size_t)r*Bk + b)*Nk + dst)*16 + fg] = make_uint2(plo, phi);
}

// ---------------------------------------------------------------------------
// MFMA projection + LN + ReLU (+ fused readout on last layer).
// Wave = 16 nodes x 64 feats. A from global (16B/lane), B = wt_hi/wt_lo.
// C/D: col=lane&15 (node), row=quad*4+reg (feat-ish; here rows = node index
// within jt-tile mapping as before). LN via xor-shuffle in 16-lane groups.
// ---------------------------------------------------------------------------
__global__ __launch_bounds__(256) void k_proj_mfma(u16* __restrict__ xh,
        const u16* __restrict__ aggh,
        const u16* __restrict__ wt_hi, const u16* __restrict__ wt_lo,
        const float* __restrict__ ln_g, const float* __restrict__ ln_b, int l,
        int last, const float* __restrict__ W_out, const float* __restrict__ b_out,
        float* __restrict__ out){
    int lane = threadIdx.x & 63;
    int wq   = threadIdx.x >> 6;
    int b    = blockIdx.y;
    int n0   = blockIdx.x*64 + wq*16;     // 16 nodes for this wave
    int mrow = lane & 15;
    int kq   = lane >> 4;
    int node_a = n0 + mrow;
    if(node_a >= Nk) node_a = Nk - 1;     // clamp; invalid rows never stored

    f32x4 acc[4];
    #pragma unroll
    for(int jt = 0; jt < 4; ++jt) acc[jt] = (f32x4){0.f,0.f,0.f,0.f};

    const u16* wl_hi = wt_hi + (size_t)l*16384;
    const u16* wl_lo = wt_lo + (size_t)l*16384;

    #pragma unroll
    for(int mt = 0; mt < 4; ++mt){
        const u16* arow = (mt == 0)
            ? xh   + ((size_t)b*Nk + node_a)*64
            : aggh + (((size_t)(mt-1)*Bk + b)*Nk + node_a)*64;
        #pragma unroll
        for(int kc = 0; kc < 2; ++kc){
            bf16x8 afrag = *(const bf16x8*)(arow + kc*32 + kq*8);
            #pragma unroll
            for(int jt = 0; jt < 4; ++jt){
                size_t wi = ((size_t)((mt*2 + kc)*4 + jt)*64 + lane)*8;
                bf16x8 bh = *(const bf16x8*)(wl_hi + wi);
                bf16x8 bl = *(const bf16x8*)(wl_lo + wi);
                acc[jt] = __builtin_amdgcn_mfma_f32_16x16x32_bf16(afrag, bh, acc[jt], 0, 0, 0);
                acc[jt] = __builtin_amdgcn_mfma_f32_16x16x32_bf16(afrag, bl, acc[jt], 0, 0, 0);
            }
        }
    }

    float gv[4], bv[4], wo[4];
    #pragma unroll
    for(int jt = 0; jt < 4; ++jt){
        int f = jt*16 + mrow;
        gv[jt] = ln_g[l*64 + f];
        bv[jt] = ln_b[l*64 + f];
        wo[jt] = W_out[f];
    }
    float bo = b_out[0];

    u16* xdst = xh + (size_t)b*Nk*64;
    #pragma unroll
    for(int v = 0; v < 4; ++v){
        float s1 = acc[0][v] + acc[1][v] + acc[2][v] + acc[3][v];
        float s2 = acc[0][v]*acc[0][v] + acc[1][v]*acc[1][v]
                 + acc[2][v]*acc[2][v] + acc[3][v]*acc[3][v];
        #pragma unroll
        for(int off = 1; off <= 8; off <<= 1){
            s1 += __shfl_xor(s1, off);
            s2 += __shfl_xor(s2, off);
        }
        float mu  = s1 * 0.015625f;
        float var = s2 * 0.015625f - mu*mu;
        float rstd = rsqrtf(var + 1e-3f);
        int node = n0 + kq*4 + v;
        if(!last){
            if(node < Nk){
                #pragma unroll
                for(int jt = 0; jt < 4; ++jt){
                    float o = (acc[jt][v] - mu) * rstd * gv[jt] + bv[jt];
                    xdst[(size_t)node*64 + jt*16 + mrow] = f2bf(fmaxf(o, 0.f));
                }
            }
        }else{
            float s3 = 0.f;
            #pragma unroll
            for(int jt = 0; jt < 4; ++jt){
                float o = (acc[jt][v] - mu) * rstd * gv[jt] + bv[jt];
                s3 += fmaxf(o, 0.f) * wo[jt];
            }
            #pragma unroll
            for(int off = 1; off <= 8; off <<= 1)
                s3 += __shfl_xor(s3, off);
            if(mrow == 0 && node < Nk)
                out[(size_t)b*Nk + node] = s3 + bo;
        }
    }
}

// ---------------------------------------------------------------------------
extern "C" void kernel_launch(void* const* d_in, const int* in_sizes, int n_in,
                              void* d_out, int out_size, void* d_ws, size_t ws_size,
                              hipStream_t stream){
    const float* ctl        = (const float*)d_in[0];
    const float* dt         = (const float*)d_in[1];
    const float* drug_fp    = (const float*)d_in[2];
    const float* edge_w     = (const float*)d_in[3];
    const int*   cell_idx   = (const int*)  d_in[4];
    const int*   edge_index = (const int*)  d_in[5];
    const float* W_se       = (const float*)d_in[6];
    const float* b_se       = (const float*)d_in[7];
    const float* cell_emb   = (const float*)d_in[8];
    const float* W_f1       = (const float*)d_in[9];
    const float* b_f1       = (const float*)d_in[10];
    const float* W_f2       = (const float*)d_in[11];
    const float* b_f2       = (const float*)d_in[12];
    const float* Wself      = (const float*)d_in[13];
    const float* Wrel       = (const float*)d_in[14];
    const float* ln_g       = (const float*)d_in[15];
    const float* ln_b       = (const float*)d_in[16];
    const float* W_out      = (const float*)d_in[17];
    const float* b_out      = (const float*)d_in[18];
    float* out = (float*)d_out;

    char* p = (char*)d_ws;
    auto alloc = [&](size_t bytes)->char*{
        char* r = p; p += (bytes + 255) & ~(size_t)255; return r;
    };
    int*   deg    = (int*)  alloc((size_t)Rk*Nk*4);
    int*   cursor = (int*)  alloc((size_t)Rk*Nk*4);
    int*   offs   = (int*)  alloc((size_t)Rk*(Nk+1)*4);
    int2*  epack  = (int2*) alloc((size_t)Rk*Ek*8);
    float* hid    = (float*)alloc((size_t)Bk*64*4);
    float* g1p    = (float*)alloc((size_t)Bk*64*4);
    float* beta   = (float*)alloc((size_t)Bk*64*4);
    u16*   xh     = (u16*)  alloc((size_t)Bk*Nk*64*2);
    u16*   aggh   = (u16*)  alloc((size_t)3*Bk*Nk*64*2);
    u16*   wt_hi  = (u16*)  alloc((size_t)Lk*16384*2);
    u16*   wt_lo  = (u16*)  alloc((size_t)Lk*16384*2);

    // CSR build (edge structure is layer-invariant; rebuilt every launch)
    k_zero<<<(Rk*Nk + 255)/256, 256, 0, stream>>>(deg, Rk*Nk);
    k_count<<<(Rk*Ek + 255)/256, 256, 0, stream>>>(edge_index, deg);
    k_scan<<<Rk, 1024, 0, stream>>>(deg, offs, cursor);
    k_fill<<<(Rk*Ek + 255)/256, 256, 0, stream>>>(edge_index, edge_w, cursor, epack);

    // weight prep for MFMA projection (all layers at once)
    k_wprep<<<(Lk*4*2*4*64*8 + 255)/256, 256, 0, stream>>>(Wself, Wrel, wt_hi, wt_lo);

    // FiLM
    k_film1<<<Bk*64, 256, 0, stream>>>(drug_fp, W_f1, b_f1, hid);
    k_film2<<<Bk, 128, 0, stream>>>(hid, W_f2, b_f2, g1p, beta);

    // x0
    k_init<<<2048, 256, 0, stream>>>(ctl, dt, cell_idx, W_se, b_se, cell_emb, g1p, beta, xh);

    // layers
    for(int l = 0; l < Lk; ++l){
        // 2 quads x 7500 groups x 4 waves; quad=blockIdx&1 matches XCD parity
        k_agg<<<2*7500, 256, 0, stream>>>(xh, offs, epack, aggh);
        k_proj_mfma<<<dim3((Nk + 63)/64, Bk), 256, 0, stream>>>(
            xh, aggh, wt_hi, wt_lo, ln_g, ln_b, l,
            (l == Lk-1) ? 1 : 0, W_out, b_out, out);
    }
}

// Round 9
// 432.764 us; speedup vs baseline: 1.9427x; 1.0487x over previous
//
#include <hip/hip_runtime.h>
#include <hip/hip_bf16.h>
#include <math.h>

#define Bk 8
#define Nk 10000
#define Hk 64
#define Lk 4
#define Rk 3
#define Ek 200000
#define FPk 2048

typedef unsigned short u16;
typedef unsigned int   u32;
typedef _Float16 f16;
typedef __attribute__((ext_vector_type(2))) _Float16 f16x2;
typedef __attribute__((ext_vector_type(8))) _Float16 f16x8;
typedef __attribute__((ext_vector_type(4))) float f32x4;

__device__ __forceinline__ f16x2 as_h2(u32 u){
    union{u32 i; f16x2 h;} v; v.i = u; return v.h;
}
__device__ __forceinline__ u32 as_u32(f16x2 h){
    union{u32 i; f16x2 h;} v; v.h = h; return v.i;
}
__device__ __forceinline__ u16 f2h_bits(float f){
    union{f16 h; u16 u;} v; v.h = (f16)f; return v.u;
}
__device__ __forceinline__ float h2f_bits(u16 u){
    union{f16 h; u16 u;} v; v.u = u; return (float)v.h;
}

// ---------------------------------------------------------------------------
// CSR build
// ---------------------------------------------------------------------------
__global__ void k_zero(int* p, int n){
    int i = blockIdx.x*256 + threadIdx.x;
    if(i < n) p[i] = 0;
}

__global__ void k_count(const int* edge_index, int* deg){
    int idx = blockIdx.x*256 + threadIdx.x;
    if(idx >= Rk*Ek) return;
    int r = idx / Ek, e = idx % Ek;
    int dst = edge_index[r*2*Ek + Ek + e];
    atomicAdd(&deg[r*Nk + dst], 1);
}

__global__ void k_scan(const int* deg, int* offs, int* cursor){
    int r = blockIdx.x;
    __shared__ int s[1024];
    __shared__ int carry;
    if(threadIdx.x == 0) carry = 0;
    __syncthreads();
    for(int base = 0; base < Nk; base += 1024){
        int i = base + threadIdx.x;
        int v = (i < Nk) ? deg[r*Nk + i] : 0;
        s[threadIdx.x] = v;
        __syncthreads();
        for(int d = 1; d < 1024; d <<= 1){
            int t = (threadIdx.x >= d) ? s[threadIdx.x - d] : 0;
            __syncthreads();
            s[threadIdx.x] += t;
            __syncthreads();
        }
        int incl = s[threadIdx.x];
        int excl = carry + incl - v;
        if(i < Nk){ offs[r*(Nk+1)+i] = excl; cursor[r*Nk+i] = excl; }
        __syncthreads();
        if(threadIdx.x == 1023) carry += s[1023];
        __syncthreads();
    }
    if(threadIdx.x == 0) offs[r*(Nk+1)+Nk] = carry;
}

// pack each edge as {src*128 (byte offset), (w,w) as packed half2}
__global__ void k_fill(const int* edge_index, const float* edge_weight,
                       int* cursor, int2* epack){
    int idx = blockIdx.x*256 + threadIdx.x;
    if(idx >= Rk*Ek) return;
    int r = idx / Ek, e = idx % Ek;
    int src = edge_index[r*2*Ek + e];
    int dst = edge_index[r*2*Ek + Ek + e];
    int pos = atomicAdd(&cursor[r*Nk + dst], 1);
    f16 h = (f16)edge_weight[r*Ek + e];
    epack[(size_t)r*Ek + pos] = make_int2(src << 7, (int)as_u32((f16x2){h, h}));
}

// ---------------------------------------------------------------------------
// Weight prep: W -> MFMA B-operand layout, fp16 (no hi/lo split needed).
// idx = (((l*4+mt)*2+kc)*4+jt)*64*8 + lane*8 + j
// B[k][n]: k = kc*32 + (lane>>4)*8 + j, n = jt*16 + (lane&15)
// ---------------------------------------------------------------------------
__global__ void k_wprep(const float* __restrict__ Wself, const float* __restrict__ Wrel,
                        u16* __restrict__ wt){
    int idx = blockIdx.x*256 + threadIdx.x;
    if(idx >= Lk*4*2*4*64*8) return;
    int j    = idx & 7;
    int lane = (idx >> 3) & 63;
    int jt   = (idx >> 9) & 3;
    int kc   = (idx >> 11) & 1;
    int mt   = (idx >> 12) & 3;
    int l    = idx >> 14;
    int k    = kc*32 + (lane >> 4)*8 + j;
    int col  = jt*16 + (lane & 15);
    float w = (mt == 0) ? Wself[(l*64 + k)*64 + col]
                        : Wrel[((l*3 + (mt-1))*64 + k)*64 + col];
    wt[idx] = f2h_bits(w);
}

// ---------------------------------------------------------------------------
// FiLM
// ---------------------------------------------------------------------------
__global__ void k_film1(const float* fp, const float* W1, const float* b1, float* hid){
    int b = blockIdx.x >> 6, h = blockIdx.x & 63;
    const float* fpb = fp + b*FPk;
    float acc = 0.f;
    for(int k = threadIdx.x; k < FPk; k += 256)
        acc += fpb[k] * W1[k*64 + h];
    __shared__ float red[256];
    red[threadIdx.x] = acc;
    __syncthreads();
    for(int s = 128; s >= 1; s >>= 1){
        if(threadIdx.x < s) red[threadIdx.x] += red[threadIdx.x + s];
        __syncthreads();
    }
    if(threadIdx.x == 0) hid[b*64 + h] = fmaxf(red[0] + b1[h], 0.f);
}

__global__ void k_film2(const float* hid, const float* W2, const float* b2,
                        float* g1p, float* beta){
    int b = blockIdx.x, j = threadIdx.x;   // 128 threads
    float acc = b2[j];
    for(int k = 0; k < 64; ++k)
        acc += hid[b*64 + k] * W2[k*128 + j];
    if(j < 64) g1p[b*64 + j] = 1.f + tanhf(acc);
    else       beta[b*64 + j - 64] = acc;
}

// ---------------------------------------------------------------------------
// x0 (fp16)
// ---------------------------------------------------------------------------
__global__ void k_init(const float* ctl, const float* dt, const int* cell_idx,
                       const float* W_se, const float* b_se, const float* cell_emb,
                       const float* g1p, const float* beta, u16* xh){
    const size_t total = (size_t)Bk*Nk*64;
    for(size_t i = (size_t)blockIdx.x*256 + threadIdx.x; i < total; i += (size_t)gridDim.x*256){
        int h = (int)(i & 63);
        size_t bn = i >> 6;
        int b = (int)(bn / Nk);
        float w = W_se[h], bs = b_se[h];
        float v = fmaxf(ctl[bn]*w + bs, 0.f) + fmaxf(dt[bn]*w + bs, 0.f)
                + cell_emb[cell_idx[b]*64 + h];
        xh[i] = f2h_bits(v * g1p[b*64 + h] + beta[b*64 + h]);
    }
}

// ---------------------------------------------------------------------------
// agg (fp16): wave = one (r,dst) x 4 batches (lane>>4) x 16 feat-quads (lane&15).
// Records: cooperative chunk -> LDS stash -> b128 broadcast (2 records/read).
// Inner math: v_pk_fma_f16 (half2 fma), 2 instrs per 4 feats; 2 accumulation
// chains (A even records, C odd) cap f16 accumulation error.
// quad=blockIdx&1 (XCD parity) -> per-XCD gather slice = 4 batches.
// ---------------------------------------------------------------------------
__global__ __launch_bounds__(256) void k_agg(const u16* __restrict__ xh,
                      const int* __restrict__ offs, const int2* __restrict__ epack,
                      u16* __restrict__ aggh){
    __shared__ int2 stash[4][64];
    int quad  = blockIdx.x & 1;
    int grp   = blockIdx.x >> 1;                   // 0..7499
    int wq    = threadIdx.x >> 6;
    int wid   = grp*4 + wq;                        // 0..29999 = (r,dst)
    int lane  = threadIdx.x & 63;
    int fg    = lane & 15;                         // feat quad: feats fg*4..+3
    int bl    = lane >> 4;                         // local batch 0..3
    int b     = quad*4 + bl;
    int r = wid / Nk, dst = wid % Nk;
    int o0 = offs[r*(Nk+1) + dst], o1 = offs[r*(Nk+1) + dst + 1];
    const int2* ep = epack + (size_t)r*Ek;
    const char* xb = (const char*)xh + (size_t)b*Nk*128 + fg*8;

    f16x2 A0 = (f16x2){0,0}, A1 = (f16x2){0,0};    // chain A
    f16x2 C0 = (f16x2){0,0}, C1 = (f16x2){0,0};    // chain C
    int2* st = stash[wq];
    for(int base = o0; base < o1; base += 64){
        int j = base + lane;
        if(j < o1) st[lane] = ep[j];
        int cnt = min(o1 - base, 64);
        int t = 0;
        for(; t + 4 <= cnt; t += 4){
            int4 q01 = *(const int4*)&st[t];       // records t, t+1
            int4 q23 = *(const int4*)&st[t+2];     // records t+2, t+3
            uint2 u0 = *(const uint2*)(xb + q01.x);
            uint2 u1 = *(const uint2*)(xb + q01.z);
            uint2 u2 = *(const uint2*)(xb + q23.x);
            uint2 u3 = *(const uint2*)(xb + q23.z);
            f16x2 w0 = as_h2(q01.y), w1 = as_h2(q01.w);
            f16x2 w2 = as_h2(q23.y), w3 = as_h2(q23.w);
            A0 += as_h2(u0.x)*w0; A1 += as_h2(u0.y)*w0;
            C0 += as_h2(u1.x)*w1; C1 += as_h2(u1.y)*w1;
            A0 += as_h2(u2.x)*w2; A1 += as_h2(u2.y)*w2;
            C0 += as_h2(u3.x)*w3; C1 += as_h2(u3.y)*w3;
        }
        for(; t < cnt; ++t){
            int2 p = st[t];
            uint2 u = *(const uint2*)(xb + p.x);
            f16x2 w = as_h2(p.y);
            A0 += as_h2(u.x)*w; A1 += as_h2(u.y)*w;
        }
    }
    float a0 = (float)A0.x + (float)C0.x;
    float a1 = (float)A0.y + (float)C0.y;
    float a2 = (float)A1.x + (float)C1.x;
    float a3 = (float)A1.y + (float)C1.y;
    u32 plo = (u32)f2h_bits(a0) | ((u32)f2h_bits(a1) << 16);
    u32 phi = (u32)f2h_bits(a2) | ((u32)f2h_bits(a3) << 16);
    ((uint2*)aggh)[(((size_t)r*Bk + b)*Nk + dst)*16 + fg] = make_uint2(plo, phi);
}

// ---------------------------------------------------------------------------
// MFMA projection (fp16) + LN + ReLU (+ fused readout on last layer).
// Wave = 16 nodes x 64 feats. A from global (16B/lane), B = wt (fp16, single).
// C/D: col=lane&15, row=quad*4+reg. LN via xor-shuffle in 16-lane groups.
// ---------------------------------------------------------------------------
__global__ __launch_bounds__(256) void k_proj_mfma(u16* __restrict__ xh,
        const u16* __restrict__ aggh, const u16* __restrict__ wt,
        const float* __restrict__ ln_g, const float* __restrict__ ln_b, int l,
        int last, const float* __restrict__ W_out, const float* __restrict__ b_out,
        float* __restrict__ out){
    int lane = threadIdx.x & 63;
    int wq   = threadIdx.x >> 6;
    int b    = blockIdx.y;
    int n0   = blockIdx.x*64 + wq*16;     // 16 nodes for this wave
    int mrow = lane & 15;
    int kq   = lane >> 4;
    int node_a = n0 + mrow;
    if(node_a >= Nk) node_a = Nk - 1;     // clamp; invalid rows never stored

    f32x4 acc[4];
    #pragma unroll
    for(int jt = 0; jt < 4; ++jt) acc[jt] = (f32x4){0.f,0.f,0.f,0.f};

    const u16* wl = wt + (size_t)l*16384;

    #pragma unroll
    for(int mt = 0; mt < 4; ++mt){
        const u16* arow = (mt == 0)
            ? xh   + ((size_t)b*Nk + node_a)*64
            : aggh + (((size_t)(mt-1)*Bk + b)*Nk + node_a)*64;
        #pragma unroll
        for(int kc = 0; kc < 2; ++kc){
            f16x8 afrag = *(const f16x8*)(arow + kc*32 + kq*8);
            #pragma unroll
            for(int jt = 0; jt < 4; ++jt){
                size_t wi = ((size_t)((mt*2 + kc)*4 + jt)*64 + lane)*8;
                f16x8 bfrag = *(const f16x8*)(wl + wi);
                acc[jt] = __builtin_amdgcn_mfma_f32_16x16x32_f16(afrag, bfrag, acc[jt], 0, 0, 0);
            }
        }
    }

    float gv[4], bv[4], wo[4];
    #pragma unroll
    for(int jt = 0; jt < 4; ++jt){
        int f = jt*16 + mrow;
        gv[jt] = ln_g[l*64 + f];
        bv[jt] = ln_b[l*64 + f];
        wo[jt] = W_out[f];
    }
    float bo = b_out[0];

    u16* xdst = xh + (size_t)b*Nk*64;
    #pragma unroll
    for(int v = 0; v < 4; ++v){
        float s1 = acc[0][v] + acc[1][v] + acc[2][v] + acc[3][v];
        float s2 = acc[0][v]*acc[0][v] + acc[1][v]*acc[1][v]
                 + acc[2][v]*acc[2][v] + acc[3][v]*acc[3][v];
        #pragma unroll
        for(int off = 1; off <= 8; off <<= 1){
            s1 += __shfl_xor(s1, off);
            s2 += __shfl_xor(s2, off);
        }
        float mu  = s1 * 0.015625f;
        float var = s2 * 0.015625f - mu*mu;
        float rstd = rsqrtf(var + 1e-3f);
        int node = n0 + kq*4 + v;
        if(!last){
            if(node < Nk){
                #pragma unroll
                for(int jt = 0; jt < 4; ++jt){
                    float o = (acc[jt][v] - mu) * rstd * gv[jt] + bv[jt];
                    xdst[(size_t)node*64 + jt*16 + mrow] = f2h_bits(fmaxf(o, 0.f));
                }
            }
        }else{
            float s3 = 0.f;
            #pragma unroll
            for(int jt = 0; jt < 4; ++jt){
                float o = (acc[jt][v] - mu) * rstd * gv[jt] + bv[jt];
                s3 += fmaxf(o, 0.f) * wo[jt];
            }
            #pragma unroll
            for(int off = 1; off <= 8; off <<= 1)
                s3 += __shfl_xor(s3, off);
            if(mrow == 0 && node < Nk)
                out[(size_t)b*Nk + node] = s3 + bo;
        }
    }
}

// ---------------------------------------------------------------------------
extern "C" void kernel_launch(void* const* d_in, const int* in_sizes, int n_in,
                              void* d_out, int out_size, void* d_ws, size_t ws_size,
                              hipStream_t stream){
    const float* ctl        = (const float*)d_in[0];
    const float* dt         = (const float*)d_in[1];
    const float* drug_fp    = (const float*)d_in[2];
    const float* edge_w     = (const float*)d_in[3];
    const int*   cell_idx   = (const int*)  d_in[4];
    const int*   edge_index = (const int*)  d_in[5];
    const float* W_se       = (const float*)d_in[6];
    const float* b_se       = (const float*)d_in[7];
    const float* cell_emb   = (const float*)d_in[8];
    const float* W_f1       = (const float*)d_in[9];
    const float* b_f1       = (const float*)d_in[10];
    const float* W_f2       = (const float*)d_in[11];
    const float* b_f2       = (const float*)d_in[12];
    const float* Wself      = (const float*)d_in[13];
    const float* Wrel       = (const float*)d_in[14];
    const float* ln_g       = (const float*)d_in[15];
    const float* ln_b       = (const float*)d_in[16];
    const float* W_out      = (const float*)d_in[17];
    const float* b_out      = (const float*)d_in[18];
    float* out = (float*)d_out;

    char* p = (char*)d_ws;
    auto alloc = [&](size_t bytes)->char*{
        char* r = p; p += (bytes + 255) & ~(size_t)255; return r;
    };
    int*   deg    = (int*)  alloc((size_t)Rk*Nk*4);
    int*   cursor = (int*)  alloc((size_t)Rk*Nk*4);
    int*   offs   = (int*)  alloc((size_t)Rk*(Nk+1)*4);
    int2*  epack  = (int2*) alloc((size_t)Rk*Ek*8);
    float* hid    = (float*)alloc((size_t)Bk*64*4);
    float* g1p    = (float*)alloc((size_t)Bk*64*4);
    float* beta   = (float*)alloc((size_t)Bk*64*4);
    u16*   xh     = (u16*)  alloc((size_t)Bk*Nk*64*2);
    u16*   aggh   = (u16*)  alloc((size_t)3*Bk*Nk*64*2);
    u16*   wt     = (u16*)  alloc((size_t)Lk*16384*2);

    // CSR build (edge structure is layer-invariant; rebuilt every launch)
    k_zero<<<(Rk*Nk + 255)/256, 256, 0, stream>>>(deg, Rk*Nk);
    k_count<<<(Rk*Ek + 255)/256, 256, 0, stream>>>(edge_index, deg);
    k_scan<<<Rk, 1024, 0, stream>>>(deg, offs, cursor);
    k_fill<<<(Rk*Ek + 255)/256, 256, 0, stream>>>(edge_index, edge_w, cursor, epack);

    // weight prep for MFMA projection (all layers at once)
    k_wprep<<<(Lk*4*2*4*64*8 + 255)/256, 256, 0, stream>>>(Wself, Wrel, wt);

    // FiLM
    k_film1<<<Bk*64, 256, 0, stream>>>(drug_fp, W_f1, b_f1, hid);
    k_film2<<<Bk, 128, 0, stream>>>(hid, W_f2, b_f2, g1p, beta);

    // x0
    k_init<<<2048, 256, 0, stream>>>(ctl, dt, cell_idx, W_se, b_se, cell_emb, g1p, beta, xh);

    // layers
    for(int l = 0; l < Lk; ++l){
        // 2 quads x 7500 groups x 4 waves; quad=blockIdx&1 matches XCD parity
        k_agg<<<2*7500, 256, 0, stream>>>(xh, offs, epack, aggh);
        k_proj_mfma<<<dim3((Nk + 63)/64, Bk), 256, 0, stream>>>(
            xh, aggh, wt, ln_g, ln_b, l,
            (l == Lk-1) ? 1 : 0, W_out, b_out, out);
    }
}

// Round 10
// 423.823 us; speedup vs baseline: 1.9837x; 1.0211x over previous
//
#include <hip/hip_runtime.h>
#include <hip/hip_bf16.h>
#include <math.h>

#define Bk 8
#define Nk 10000
#define Hk 64
#define Lk 4
#define Rk 3
#define Ek 200000
#define FPk 2048

typedef unsigned short u16;
typedef unsigned int   u32;
typedef _Float16 f16;
typedef __attribute__((ext_vector_type(2))) _Float16 f16x2;
typedef __attribute__((ext_vector_type(8))) _Float16 f16x8;
typedef __attribute__((ext_vector_type(4))) float f32x4;

__device__ __forceinline__ f16x2 as_h2(u32 u){
    union{u32 i; f16x2 h;} v; v.i = u; return v.h;
}
__device__ __forceinline__ u32 as_u32(f16x2 h){
    union{u32 i; f16x2 h;} v; v.h = h; return v.i;
}
__device__ __forceinline__ u16 f2h_bits(float f){
    union{f16 h; u16 u;} v; v.h = (f16)f; return v.u;
}

// ---------------------------------------------------------------------------
// CSR build
// ---------------------------------------------------------------------------
__global__ void k_zero(int* p, int n){
    int i = blockIdx.x*256 + threadIdx.x;
    if(i < n) p[i] = 0;
}

__global__ void k_count(const int* edge_index, int* deg){
    int idx = blockIdx.x*256 + threadIdx.x;
    if(idx >= Rk*Ek) return;
    int r = idx / Ek, e = idx % Ek;
    int dst = edge_index[r*2*Ek + Ek + e];
    atomicAdd(&deg[r*Nk + dst], 1);
}

// one block per relation; thread t owns elements [t*10, t*10+10); single
// 1024-wide Hillis-Steele over per-thread sums (1 scan round, not 10)
__global__ void k_scan(const int* deg, int* offs, int* cursor){
    int r = blockIdx.x;
    __shared__ int s[1024];
    int t = threadIdx.x;
    int base_i = t*10;
    int local[10];
    int sum = 0;
    if(base_i < Nk){
        #pragma unroll
        for(int k = 0; k < 10; ++k){ local[k] = deg[r*Nk + base_i + k]; sum += local[k]; }
    }
    s[t] = sum;
    __syncthreads();
    for(int d = 1; d < 1024; d <<= 1){
        int v = (t >= d) ? s[t-d] : 0;
        __syncthreads();
        s[t] += v;
        __syncthreads();
    }
    if(base_i < Nk){
        int excl = s[t] - sum;
        #pragma unroll
        for(int k = 0; k < 10; ++k){
            offs[r*(Nk+1) + base_i + k] = excl;
            cursor[r*Nk + base_i + k]   = excl;
            excl += local[k];
        }
    }
    if(t == 1023) offs[r*(Nk+1) + Nk] = s[1023];
}

// pack each edge as {src*128 (byte offset), (w,w) as packed half2}
__global__ void k_fill(const int* edge_index, const float* edge_weight,
                       int* cursor, int2* epack){
    int idx = blockIdx.x*256 + threadIdx.x;
    if(idx >= Rk*Ek) return;
    int r = idx / Ek, e = idx % Ek;
    int src = edge_index[r*2*Ek + e];
    int dst = edge_index[r*2*Ek + Ek + e];
    int pos = atomicAdd(&cursor[r*Nk + dst], 1);
    f16 h = (f16)edge_weight[r*Ek + e];
    epack[(size_t)r*Ek + pos] = make_int2(src << 7, (int)as_u32((f16x2){h, h}));
}

// ---------------------------------------------------------------------------
// Weight prep: W -> MFMA B-operand layout, fp16.
// ---------------------------------------------------------------------------
__global__ void k_wprep(const float* __restrict__ Wself, const float* __restrict__ Wrel,
                        u16* __restrict__ wt){
    int idx = blockIdx.x*256 + threadIdx.x;
    if(idx >= Lk*4*2*4*64*8) return;
    int j    = idx & 7;
    int lane = (idx >> 3) & 63;
    int jt   = (idx >> 9) & 3;
    int kc   = (idx >> 11) & 1;
    int mt   = (idx >> 12) & 3;
    int l    = idx >> 14;
    int k    = kc*32 + (lane >> 4)*8 + j;
    int col  = jt*16 + (lane & 15);
    float w = (mt == 0) ? Wself[(l*64 + k)*64 + col]
                        : Wrel[((l*3 + (mt-1))*64 + k)*64 + col];
    wt[idx] = f2h_bits(w);
}

// ---------------------------------------------------------------------------
// FiLM
// ---------------------------------------------------------------------------
__global__ void k_film1(const float* fp, const float* W1, const float* b1, float* hid){
    int b = blockIdx.x >> 6, h = blockIdx.x & 63;
    const float* fpb = fp + b*FPk;
    float acc = 0.f;
    for(int k = threadIdx.x; k < FPk; k += 256)
        acc += fpb[k] * W1[k*64 + h];
    __shared__ float red[256];
    red[threadIdx.x] = acc;
    __syncthreads();
    for(int s = 128; s >= 1; s >>= 1){
        if(threadIdx.x < s) red[threadIdx.x] += red[threadIdx.x + s];
        __syncthreads();
    }
    if(threadIdx.x == 0) hid[b*64 + h] = fmaxf(red[0] + b1[h], 0.f);
}

__global__ void k_film2(const float* hid, const float* W2, const float* b2,
                        float* g1p, float* beta){
    int b = blockIdx.x, j = threadIdx.x;   // 128 threads
    float acc = b2[j];
    for(int k = 0; k < 64; ++k)
        acc += hid[b*64 + k] * W2[k*128 + j];
    if(j < 64) g1p[b*64 + j] = 1.f + tanhf(acc);
    else       beta[b*64 + j - 64] = acc;
}

// ---------------------------------------------------------------------------
// x0 (fp16)
// ---------------------------------------------------------------------------
__global__ void k_init(const float* ctl, const float* dt, const int* cell_idx,
                       const float* W_se, const float* b_se, const float* cell_emb,
                       const float* g1p, const float* beta, u16* xh){
    const size_t total = (size_t)Bk*Nk*64;
    for(size_t i = (size_t)blockIdx.x*256 + threadIdx.x; i < total; i += (size_t)gridDim.x*256){
        int h = (int)(i & 63);
        size_t bn = i >> 6;
        int b = (int)(bn / Nk);
        float w = W_se[h], bs = b_se[h];
        float v = fmaxf(ctl[bn]*w + bs, 0.f) + fmaxf(dt[bn]*w + bs, 0.f)
                + cell_emb[cell_idx[b]*64 + h];
        xh[i] = f2h_bits(v * g1p[b*64 + h] + beta[b*64 + h]);
    }
}

// ---------------------------------------------------------------------------
// agg (fp16): wave = one (r,dst) x 4 batches (lane>>4) x 16 feat-quads (lane&15).
// Records: cooperative chunk -> LDS stash -> b128 broadcast (2 records/read).
// 8 gathers in flight (MLP=8); v_pk_fma_f16 math; 2 accumulation chains.
// quad=blockIdx&1 (XCD parity) -> per-XCD gather slice = 4 batches.
// ---------------------------------------------------------------------------
__global__ __launch_bounds__(256) void k_agg(const u16* __restrict__ xh,
                      const int* __restrict__ offs, const int2* __restrict__ epack,
                      u16* __restrict__ aggh){
    __shared__ int2 stash[4][64];
    int quad  = blockIdx.x & 1;
    int grp   = blockIdx.x >> 1;                   // 0..7499
    int wq    = threadIdx.x >> 6;
    int wid   = grp*4 + wq;                        // 0..29999 = (r,dst)
    int lane  = threadIdx.x & 63;
    int fg    = lane & 15;                         // feat quad: feats fg*4..+3
    int bl    = lane >> 4;                         // local batch 0..3
    int b     = quad*4 + bl;
    int r = wid / Nk, dst = wid % Nk;
    int o0 = offs[r*(Nk+1) + dst], o1 = offs[r*(Nk+1) + dst + 1];
    const int2* ep = epack + (size_t)r*Ek;
    const char* xb = (const char*)xh + (size_t)b*Nk*128 + fg*8;

    f16x2 A0 = (f16x2){0,0}, A1 = (f16x2){0,0};    // chain A
    f16x2 C0 = (f16x2){0,0}, C1 = (f16x2){0,0};    // chain C
    int2* st = stash[wq];
    for(int base = o0; base < o1; base += 64){
        int j = base + lane;
        if(j < o1) st[lane] = ep[j];
        int cnt = min(o1 - base, 64);
        int t = 0;
        for(; t + 8 <= cnt; t += 8){
            int4 q01 = *(const int4*)&st[t];
            int4 q23 = *(const int4*)&st[t+2];
            int4 q45 = *(const int4*)&st[t+4];
            int4 q67 = *(const int4*)&st[t+6];
            uint2 u0 = *(const uint2*)(xb + q01.x);
            uint2 u1 = *(const uint2*)(xb + q01.z);
            uint2 u2 = *(const uint2*)(xb + q23.x);
            uint2 u3 = *(const uint2*)(xb + q23.z);
            uint2 u4 = *(const uint2*)(xb + q45.x);
            uint2 u5 = *(const uint2*)(xb + q45.z);
            uint2 u6 = *(const uint2*)(xb + q67.x);
            uint2 u7 = *(const uint2*)(xb + q67.z);
            f16x2 w0 = as_h2(q01.y), w1 = as_h2(q01.w);
            f16x2 w2 = as_h2(q23.y), w3 = as_h2(q23.w);
            f16x2 w4 = as_h2(q45.y), w5 = as_h2(q45.w);
            f16x2 w6 = as_h2(q67.y), w7 = as_h2(q67.w);
            A0 += as_h2(u0.x)*w0; A1 += as_h2(u0.y)*w0;
            C0 += as_h2(u1.x)*w1; C1 += as_h2(u1.y)*w1;
            A0 += as_h2(u2.x)*w2; A1 += as_h2(u2.y)*w2;
            C0 += as_h2(u3.x)*w3; C1 += as_h2(u3.y)*w3;
            A0 += as_h2(u4.x)*w4; A1 += as_h2(u4.y)*w4;
            C0 += as_h2(u5.x)*w5; C1 += as_h2(u5.y)*w5;
            A0 += as_h2(u6.x)*w6; A1 += as_h2(u6.y)*w6;
            C0 += as_h2(u7.x)*w7; C1 += as_h2(u7.y)*w7;
        }
        for(; t + 4 <= cnt; t += 4){
            int4 q01 = *(const int4*)&st[t];
            int4 q23 = *(const int4*)&st[t+2];
            uint2 u0 = *(const uint2*)(xb + q01.x);
            uint2 u1 = *(const uint2*)(xb + q01.z);
            uint2 u2 = *(const uint2*)(xb + q23.x);
            uint2 u3 = *(const uint2*)(xb + q23.z);
            f16x2 w0 = as_h2(q01.y), w1 = as_h2(q01.w);
            f16x2 w2 = as_h2(q23.y), w3 = as_h2(q23.w);
            A0 += as_h2(u0.x)*w0; A1 += as_h2(u0.y)*w0;
            C0 += as_h2(u1.x)*w1; C1 += as_h2(u1.y)*w1;
            A0 += as_h2(u2.x)*w2; A1 += as_h2(u2.y)*w2;
            C0 += as_h2(u3.x)*w3; C1 += as_h2(u3.y)*w3;
        }
        for(; t < cnt; ++t){
            int2 p = st[t];
            uint2 u = *(const uint2*)(xb + p.x);
            f16x2 w = as_h2(p.y);
            A0 += as_h2(u.x)*w; A1 += as_h2(u.y)*w;
        }
    }
    float a0 = (float)A0.x + (float)C0.x;
    float a1 = (float)A0.y + (float)C0.y;
    float a2 = (float)A1.x + (float)C1.x;
    float a3 = (float)A1.y + (float)C1.y;
    u32 plo = (u32)f2h_bits(a0) | ((u32)f2h_bits(a1) << 16);
    u32 phi = (u32)f2h_bits(a2) | ((u32)f2h_bits(a3) << 16);
    ((uint2*)aggh)[(((size_t)r*Bk + b)*Nk + dst)*16 + fg] = make_uint2(plo, phi);
}

// ---------------------------------------------------------------------------
// MFMA projection (fp16) + LN + ReLU (+ fused readout on last layer).
// ---------------------------------------------------------------------------
__global__ __launch_bounds__(256) void k_proj_mfma(u16* __restrict__ xh,
        const u16* __restrict__ aggh, const u16* __restrict__ wt,
        const float* __restrict__ ln_g, const float* __restrict__ ln_b, int l,
        int last, const float* __restrict__ W_out, const float* __restrict__ b_out,
        float* __restrict__ out){
    int lane = threadIdx.x & 63;
    int wq   = threadIdx.x >> 6;
    int b    = blockIdx.y;
    int n0   = blockIdx.x*64 + wq*16;     // 16 nodes for this wave
    int mrow = lane & 15;
    int kq   = lane >> 4;
    int node_a = n0 + mrow;
    if(node_a >= Nk) node_a = Nk - 1;     // clamp; invalid rows never stored

    f32x4 acc[4];
    #pragma unroll
    for(int jt = 0; jt < 4; ++jt) acc[jt] = (f32x4){0.f,0.f,0.f,0.f};

    const u16* wl = wt + (size_t)l*16384;

    #pragma unroll
    for(int mt = 0; mt < 4; ++mt){
        const u16* arow = (mt == 0)
            ? xh   + ((size_t)b*Nk + node_a)*64
            : aggh + (((size_t)(mt-1)*Bk + b)*Nk + node_a)*64;
        #pragma unroll
        for(int kc = 0; kc < 2; ++kc){
            f16x8 afrag = *(const f16x8*)(arow + kc*32 + kq*8);
            #pragma unroll
            for(int jt = 0; jt < 4; ++jt){
                size_t wi = ((size_t)((mt*2 + kc)*4 + jt)*64 + lane)*8;
                f16x8 bfrag = *(const f16x8*)(wl + wi);
                acc[jt] = __builtin_amdgcn_mfma_f32_16x16x32_f16(afrag, bfrag, acc[jt], 0, 0, 0);
            }
        }
    }

    float gv[4], bv[4], wo[4];
    #pragma unroll
    for(int jt = 0; jt < 4; ++jt){
        int f = jt*16 + mrow;
        gv[jt] = ln_g[l*64 + f];
        bv[jt] = ln_b[l*64 + f];
        wo[jt] = W_out[f];
    }
    float bo = b_out[0];

    u16* xdst = xh + (size_t)b*Nk*64;
    #pragma unroll
    for(int v = 0; v < 4; ++v){
        float s1 = acc[0][v] + acc[1][v] + acc[2][v] + acc[3][v];
        float s2 = acc[0][v]*acc[0][v] + acc[1][v]*acc[1][v]
                 + acc[2][v]*acc[2][v] + acc[3][v]*acc[3][v];
        #pragma unroll
        for(int off = 1; off <= 8; off <<= 1){
            s1 += __shfl_xor(s1, off);
            s2 += __shfl_xor(s2, off);
        }
        float mu  = s1 * 0.015625f;
        float var = s2 * 0.015625f - mu*mu;
        float rstd = rsqrtf(var + 1e-3f);
        int node = n0 + kq*4 + v;
        if(!last){
            if(node < Nk){
                #pragma unroll
                for(int jt = 0; jt < 4; ++jt){
                    float o = (acc[jt][v] - mu) * rstd * gv[jt] + bv[jt];
                    xdst[(size_t)node*64 + jt*16 + mrow] = f2h_bits(fmaxf(o, 0.f));
                }
            }
        }else{
            float s3 = 0.f;
            #pragma unroll
            for(int jt = 0; jt < 4; ++jt){
                float o = (acc[jt][v] - mu) * rstd * gv[jt] + bv[jt];
                s3 += fmaxf(o, 0.f) * wo[jt];
            }
            #pragma unroll
            for(int off = 1; off <= 8; off <<= 1)
                s3 += __shfl_xor(s3, off);
            if(mrow == 0 && node < Nk)
                out[(size_t)b*Nk + node] = s3 + bo;
        }
    }
}

// ---------------------------------------------------------------------------
extern "C" void kernel_launch(void* const* d_in, const int* in_sizes, int n_in,
                              void* d_out, int out_size, void* d_ws, size_t ws_size,
                              hipStream_t stream){
    const float* ctl        = (const float*)d_in[0];
    const float* dt         = (const float*)d_in[1];
    const float* drug_fp    = (const float*)d_in[2];
    const float* edge_w     = (const float*)d_in[3];
    const int*   cell_idx   = (const int*)  d_in[4];
    const int*   edge_index = (const int*)  d_in[5];
    const float* W_se       = (const float*)d_in[6];
    const float* b_se       = (const float*)d_in[7];
    const float* cell_emb   = (const float*)d_in[8];
    const float* W_f1       = (const float*)d_in[9];
    const float* b_f1       = (const float*)d_in[10];
    const float* W_f2       = (const float*)d_in[11];
    const float* b_f2       = (const float*)d_in[12];
    const float* Wself      = (const float*)d_in[13];
    const float* Wrel       = (const float*)d_in[14];
    const float* ln_g       = (const float*)d_in[15];
    const float* ln_b       = (const float*)d_in[16];
    const float* W_out      = (const float*)d_in[17];
    const float* b_out      = (const float*)d_in[18];
    float* out = (float*)d_out;

    char* p = (char*)d_ws;
    auto alloc = [&](size_t bytes)->char*{
        char* r = p; p += (bytes + 255) & ~(size_t)255; return r;
    };
    int*   deg    = (int*)  alloc((size_t)Rk*Nk*4);
    int*   cursor = (int*)  alloc((size_t)Rk*Nk*4);
    int*   offs   = (int*)  alloc((size_t)Rk*(Nk+1)*4);
    int2*  epack  = (int2*) alloc((size_t)Rk*Ek*8);
    float* hid    = (float*)alloc((size_t)Bk*64*4);
    float* g1p    = (float*)alloc((size_t)Bk*64*4);
    float* beta   = (float*)alloc((size_t)Bk*64*4);
    u16*   xh     = (u16*)  alloc((size_t)Bk*Nk*64*2);
    u16*   aggh   = (u16*)  alloc((size_t)3*Bk*Nk*64*2);
    u16*   wt     = (u16*)  alloc((size_t)Lk*16384*2);

    // CSR build (edge structure is layer-invariant; rebuilt every launch)
    k_zero<<<(Rk*Nk + 255)/256, 256, 0, stream>>>(deg, Rk*Nk);
    k_count<<<(Rk*Ek + 255)/256, 256, 0, stream>>>(edge_index, deg);
    k_scan<<<Rk, 1024, 0, stream>>>(deg, offs, cursor);
    k_fill<<<(Rk*Ek + 255)/256, 256, 0, stream>>>(edge_index, edge_w, cursor, epack);

    // weight prep for MFMA projection (all layers at once)
    k_wprep<<<(Lk*4*2*4*64*8 + 255)/256, 256, 0, stream>>>(Wself, Wrel, wt);

    // FiLM
    k_film1<<<Bk*64, 256, 0, stream>>>(drug_fp, W_f1, b_f1, hid);
    k_film2<<<Bk, 128, 0, stream>>>(hid, W_f2, b_f2, g1p, beta);

    // x0
    k_init<<<2048, 256, 0, stream>>>(ctl, dt, cell_idx, W_se, b_se, cell_emb, g1p, beta, xh);

    // layers
    for(int l = 0; l < Lk; ++l){
        // 2 quads x 7500 groups x 4 waves; quad=blockIdx&1 matches XCD parity
        k_agg<<<2*7500, 256, 0, stream>>>(xh, offs, epack, aggh);
        k_proj_mfma<<<dim3((Nk + 63)/64, Bk), 256, 0, stream>>>(
            xh, aggh, wt, ln_g, ln_b, l,
            (l == Lk-1) ? 1 : 0, W_out, b_out, out);
    }
}

// Round 11
// 422.822 us; speedup vs baseline: 1.9884x; 1.0024x over previous
//
#include <hip/hip_runtime.h>
#include <hip/hip_bf16.h>
#include <math.h>

#define Bk 8
#define Nk 10000
#define Hk 64
#define Lk 4
#define Rk 3
#define Ek 200000
#define FPk 2048

typedef unsigned short u16;
typedef unsigned int   u32;
typedef _Float16 f16;
typedef __attribute__((ext_vector_type(2))) _Float16 f16x2;
typedef __attribute__((ext_vector_type(8))) _Float16 f16x8;
typedef __attribute__((ext_vector_type(4))) float f32x4;

__device__ __forceinline__ f16x2 as_h2(u32 u){
    union{u32 i; f16x2 h;} v; v.i = u; return v.h;
}
__device__ __forceinline__ u32 as_u32(f16x2 h){
    union{u32 i; f16x2 h;} v; v.h = h; return v.i;
}
__device__ __forceinline__ u16 f2h_bits(float f){
    union{f16 h; u16 u;} v; v.h = (f16)f; return v.u;
}

// ---------------------------------------------------------------------------
// CSR build
// ---------------------------------------------------------------------------
__global__ void k_zero(int* p, int n){
    int i = blockIdx.x*256 + threadIdx.x;
    if(i < n) p[i] = 0;
}

__global__ void k_count(const int* edge_index, int* deg){
    int idx = blockIdx.x*256 + threadIdx.x;
    if(idx >= Rk*Ek) return;
    int r = idx / Ek, e = idx % Ek;
    int dst = edge_index[r*2*Ek + Ek + e];
    atomicAdd(&deg[r*Nk + dst], 1);
}

// one block per relation; thread t owns elements [t*10, t*10+10); single
// 1024-wide Hillis-Steele over per-thread sums
__global__ void k_scan(const int* deg, int* offs, int* cursor){
    int r = blockIdx.x;
    __shared__ int s[1024];
    int t = threadIdx.x;
    int base_i = t*10;
    int local[10];
    int sum = 0;
    if(base_i < Nk){
        #pragma unroll
        for(int k = 0; k < 10; ++k){ local[k] = deg[r*Nk + base_i + k]; sum += local[k]; }
    }
    s[t] = sum;
    __syncthreads();
    for(int d = 1; d < 1024; d <<= 1){
        int v = (t >= d) ? s[t-d] : 0;
        __syncthreads();
        s[t] += v;
        __syncthreads();
    }
    if(base_i < Nk){
        int excl = s[t] - sum;
        #pragma unroll
        for(int k = 0; k < 10; ++k){
            offs[r*(Nk+1) + base_i + k] = excl;
            cursor[r*Nk + base_i + k]   = excl;
            excl += local[k];
        }
    }
    if(t == 1023) offs[r*(Nk+1) + Nk] = s[1023];
}

// pack each edge as {src*128 (byte offset), (w,w) as packed half2}
__global__ void k_fill(const int* edge_index, const float* edge_weight,
                       int* cursor, int2* epack){
    int idx = blockIdx.x*256 + threadIdx.x;
    if(idx >= Rk*Ek) return;
    int r = idx / Ek, e = idx % Ek;
    int src = edge_index[r*2*Ek + e];
    int dst = edge_index[r*2*Ek + Ek + e];
    int pos = atomicAdd(&cursor[r*Nk + dst], 1);
    f16 h = (f16)edge_weight[r*Ek + e];
    epack[(size_t)r*Ek + pos] = make_int2(src << 7, (int)as_u32((f16x2){h, h}));
}

// ---------------------------------------------------------------------------
// Weight prep: W -> MFMA B-operand layout, fp16.
// ---------------------------------------------------------------------------
__global__ void k_wprep(const float* __restrict__ Wself, const float* __restrict__ Wrel,
                        u16* __restrict__ wt){
    int idx = blockIdx.x*256 + threadIdx.x;
    if(idx >= Lk*4*2*4*64*8) return;
    int j    = idx & 7;
    int lane = (idx >> 3) & 63;
    int jt   = (idx >> 9) & 3;
    int kc   = (idx >> 11) & 1;
    int mt   = (idx >> 12) & 3;
    int l    = idx >> 14;
    int k    = kc*32 + (lane >> 4)*8 + j;
    int col  = jt*16 + (lane & 15);
    float w = (mt == 0) ? Wself[(l*64 + k)*64 + col]
                        : Wrel[((l*3 + (mt-1))*64 + k)*64 + col];
    wt[idx] = f2h_bits(w);
}

// ---------------------------------------------------------------------------
// FiLM
// ---------------------------------------------------------------------------
__global__ void k_film1(const float* fp, const float* W1, const float* b1, float* hid){
    int b = blockIdx.x >> 6, h = blockIdx.x & 63;
    const float* fpb = fp + b*FPk;
    float acc = 0.f;
    for(int k = threadIdx.x; k < FPk; k += 256)
        acc += fpb[k] * W1[k*64 + h];
    __shared__ float red[256];
    red[threadIdx.x] = acc;
    __syncthreads();
    for(int s = 128; s >= 1; s >>= 1){
        if(threadIdx.x < s) red[threadIdx.x] += red[threadIdx.x + s];
        __syncthreads();
    }
    if(threadIdx.x == 0) hid[b*64 + h] = fmaxf(red[0] + b1[h], 0.f);
}

__global__ void k_film2(const float* hid, const float* W2, const float* b2,
                        float* g1p, float* beta){
    int b = blockIdx.x, j = threadIdx.x;   // 128 threads
    float acc = b2[j];
    for(int k = 0; k < 64; ++k)
        acc += hid[b*64 + k] * W2[k*128 + j];
    if(j < 64) g1p[b*64 + j] = 1.f + tanhf(acc);
    else       beta[b*64 + j - 64] = acc;
}

// ---------------------------------------------------------------------------
// x0 (fp16)
// ---------------------------------------------------------------------------
__global__ void k_init(const float* ctl, const float* dt, const int* cell_idx,
                       const float* W_se, const float* b_se, const float* cell_emb,
                       const float* g1p, const float* beta, u16* xh){
    const size_t total = (size_t)Bk*Nk*64;
    for(size_t i = (size_t)blockIdx.x*256 + threadIdx.x; i < total; i += (size_t)gridDim.x*256){
        int h = (int)(i & 63);
        size_t bn = i >> 6;
        int b = (int)(bn / Nk);
        float w = W_se[h], bs = b_se[h];
        float v = fmaxf(ctl[bn]*w + bs, 0.f) + fmaxf(dt[bn]*w + bs, 0.f)
                + cell_emb[cell_idx[b]*64 + h];
        xh[i] = f2h_bits(v * g1p[b*64 + h] + beta[b*64 + h]);
    }
}

// ---------------------------------------------------------------------------
// agg (fp16): wave = one (r,dst) x 2 batches (lane>>5) x 32 feat-dwords (lane&31).
// Each gather = global_load_dword, 32 lanes x 4B = one fully-coalesced 128B row
// per batch. Records via LDS stash + b128 reads; 8 gathers in flight; pk_fma.
// bpair = blockIdx&3 -> each XCD's gather slice = 2 batches = 2.56MB, L2-hit.
// ---------------------------------------------------------------------------
__global__ __launch_bounds__(256) void k_agg(const u16* __restrict__ xh,
                      const int* __restrict__ offs, const int2* __restrict__ epack,
                      u16* __restrict__ aggh){
    __shared__ int2 stash[4][64];
    int bpair = blockIdx.x & 3;
    int grp   = blockIdx.x >> 2;                   // 0..7499
    int wq    = threadIdx.x >> 6;
    int wid   = grp*4 + wq;                        // 0..29999 = (r,dst)
    int lane  = threadIdx.x & 63;
    int fg    = lane & 31;                         // feat dword: feats fg*2, fg*2+1
    int bl    = lane >> 5;                         // local batch 0/1
    int b     = bpair*2 + bl;
    int r = wid / Nk, dst = wid % Nk;
    int o0 = offs[r*(Nk+1) + dst], o1 = offs[r*(Nk+1) + dst + 1];
    const int2* ep = epack + (size_t)r*Ek;
    const char* xb = (const char*)xh + (size_t)b*Nk*128 + fg*4;

    f16x2 A = (f16x2){0,0}, C = (f16x2){0,0};      // 2 accumulation chains
    int2* st = stash[wq];
    for(int base = o0; base < o1; base += 64){
        int j = base + lane;
        if(j < o1) st[lane] = ep[j];
        int cnt = min(o1 - base, 64);
        int t = 0;
        for(; t + 8 <= cnt; t += 8){
            int4 q01 = *(const int4*)&st[t];
            int4 q23 = *(const int4*)&st[t+2];
            int4 q45 = *(const int4*)&st[t+4];
            int4 q67 = *(const int4*)&st[t+6];
            u32 u0 = *(const u32*)(xb + q01.x);
            u32 u1 = *(const u32*)(xb + q01.z);
            u32 u2 = *(const u32*)(xb + q23.x);
            u32 u3 = *(const u32*)(xb + q23.z);
            u32 u4 = *(const u32*)(xb + q45.x);
            u32 u5 = *(const u32*)(xb + q45.z);
            u32 u6 = *(const u32*)(xb + q67.x);
            u32 u7 = *(const u32*)(xb + q67.z);
            A += as_h2(u0)*as_h2(q01.y); C += as_h2(u1)*as_h2(q01.w);
            A += as_h2(u2)*as_h2(q23.y); C += as_h2(u3)*as_h2(q23.w);
            A += as_h2(u4)*as_h2(q45.y); C += as_h2(u5)*as_h2(q45.w);
            A += as_h2(u6)*as_h2(q67.y); C += as_h2(u7)*as_h2(q67.w);
        }
        for(; t + 2 <= cnt; t += 2){
            int4 q01 = *(const int4*)&st[t];
            u32 u0 = *(const u32*)(xb + q01.x);
            u32 u1 = *(const u32*)(xb + q01.z);
            A += as_h2(u0)*as_h2(q01.y); C += as_h2(u1)*as_h2(q01.w);
        }
        if(t < cnt){
            int2 p = st[t];
            u32 u = *(const u32*)(xb + p.x);
            A += as_h2(u)*as_h2(p.y);
        }
    }
    float a0 = (float)A.x + (float)C.x;
    float a1 = (float)A.y + (float)C.y;
    u32 packed = (u32)f2h_bits(a0) | ((u32)f2h_bits(a1) << 16);
    ((u32*)aggh)[(((size_t)r*Bk + b)*Nk + dst)*32 + fg] = packed;
}

// ---------------------------------------------------------------------------
// MFMA projection (fp16) + LN + ReLU (+ fused readout on last layer).
// ---------------------------------------------------------------------------
__global__ __launch_bounds__(256) void k_proj_mfma(u16* __restrict__ xh,
        const u16* __restrict__ aggh, const u16* __restrict__ wt,
        const float* __restrict__ ln_g, const float* __restrict__ ln_b, int l,
        int last, const float* __restrict__ W_out, const float* __restrict__ b_out,
        float* __restrict__ out){
    int lane = threadIdx.x & 63;
    int wq   = threadIdx.x >> 6;
    int b    = blockIdx.y;
    int n0   = blockIdx.x*64 + wq*16;     // 16 nodes for this wave
    int mrow = lane & 15;
    int kq   = lane >> 4;
    int node_a = n0 + mrow;
    if(node_a >= Nk) node_a = Nk - 1;     // clamp; invalid rows never stored

    f32x4 acc[4];
    #pragma unroll
    for(int jt = 0; jt < 4; ++jt) acc[jt] = (f32x4){0.f,0.f,0.f,0.f};

    const u16* wl = wt + (size_t)l*16384;

    #pragma unroll
    for(int mt = 0; mt < 4; ++mt){
        const u16* arow = (mt == 0)
            ? xh   + ((size_t)b*Nk + node_a)*64
            : aggh + (((size_t)(mt-1)*Bk + b)*Nk + node_a)*64;
        #pragma unroll
        for(int kc = 0; kc < 2; ++kc){
            f16x8 afrag = *(const f16x8*)(arow + kc*32 + kq*8);
            #pragma unroll
            for(int jt = 0; jt < 4; ++jt){
                size_t wi = ((size_t)((mt*2 + kc)*4 + jt)*64 + lane)*8;
                f16x8 bfrag = *(const f16x8*)(wl + wi);
                acc[jt] = __builtin_amdgcn_mfma_f32_16x16x32_f16(afrag, bfrag, acc[jt], 0, 0, 0);
            }
        }
    }

    float gv[4], bv[4], wo[4];
    #pragma unroll
    for(int jt = 0; jt < 4; ++jt){
        int f = jt*16 + mrow;
        gv[jt] = ln_g[l*64 + f];
        bv[jt] = ln_b[l*64 + f];
        wo[jt] = W_out[f];
    }
    float bo = b_out[0];

    u16* xdst = xh + (size_t)b*Nk*64;
    #pragma unroll
    for(int v = 0; v < 4; ++v){
        float s1 = acc[0][v] + acc[1][v] + acc[2][v] + acc[3][v];
        float s2 = acc[0][v]*acc[0][v] + acc[1][v]*acc[1][v]
                 + acc[2][v]*acc[2][v] + acc[3][v]*acc[3][v];
        #pragma unroll
        for(int off = 1; off <= 8; off <<= 1){
            s1 += __shfl_xor(s1, off);
            s2 += __shfl_xor(s2, off);
        }
        float mu  = s1 * 0.015625f;
        float var = s2 * 0.015625f - mu*mu;
        float rstd = rsqrtf(var + 1e-3f);
        int node = n0 + kq*4 + v;
        if(!last){
            if(node < Nk){
                #pragma unroll
                for(int jt = 0; jt < 4; ++jt){
                    float o = (acc[jt][v] - mu) * rstd * gv[jt] + bv[jt];
                    xdst[(size_t)node*64 + jt*16 + mrow] = f2h_bits(fmaxf(o, 0.f));
                }
            }
        }else{
            float s3 = 0.f;
            #pragma unroll
            for(int jt = 0; jt < 4; ++jt){
                float o = (acc[jt][v] - mu) * rstd * gv[jt] + bv[jt];
                s3 += fmaxf(o, 0.f) * wo[jt];
            }
            #pragma unroll
            for(int off = 1; off <= 8; off <<= 1)
                s3 += __shfl_xor(s3, off);
            if(mrow == 0 && node < Nk)
                out[(size_t)b*Nk + node] = s3 + bo;
        }
    }
}

// ---------------------------------------------------------------------------
extern "C" void kernel_launch(void* const* d_in, const int* in_sizes, int n_in,
                              void* d_out, int out_size, void* d_ws, size_t ws_size,
                              hipStream_t stream){
    const float* ctl        = (const float*)d_in[0];
    const float* dt         = (const float*)d_in[1];
    const float* drug_fp    = (const float*)d_in[2];
    const float* edge_w     = (const float*)d_in[3];
    const int*   cell_idx   = (const int*)  d_in[4];
    const int*   edge_index = (const int*)  d_in[5];
    const float* W_se       = (const float*)d_in[6];
    const float* b_se       = (const float*)d_in[7];
    const float* cell_emb   = (const float*)d_in[8];
    const float* W_f1       = (const float*)d_in[9];
    const float* b_f1       = (const float*)d_in[10];
    const float* W_f2       = (const float*)d_in[11];
    const float* b_f2       = (const float*)d_in[12];
    const float* Wself      = (const float*)d_in[13];
    const float* Wrel       = (const float*)d_in[14];
    const float* ln_g       = (const float*)d_in[15];
    const float* ln_b       = (const float*)d_in[16];
    const float* W_out      = (const float*)d_in[17];
    const float* b_out      = (const float*)d_in[18];
    float* out = (float*)d_out;

    char* p = (char*)d_ws;
    auto alloc = [&](size_t bytes)->char*{
        char* r = p; p += (bytes + 255) & ~(size_t)255; return r;
    };
    int*   deg    = (int*)  alloc((size_t)Rk*Nk*4);
    int*   cursor = (int*)  alloc((size_t)Rk*Nk*4);
    int*   offs   = (int*)  alloc((size_t)Rk*(Nk+1)*4);
    int2*  epack  = (int2*) alloc((size_t)Rk*Ek*8);
    float* hid    = (float*)alloc((size_t)Bk*64*4);
    float* g1p    = (float*)alloc((size_t)Bk*64*4);
    float* beta   = (float*)alloc((size_t)Bk*64*4);
    u16*   xh     = (u16*)  alloc((size_t)Bk*Nk*64*2);
    u16*   aggh   = (u16*)  alloc((size_t)3*Bk*Nk*64*2);
    u16*   wt     = (u16*)  alloc((size_t)Lk*16384*2);

    // CSR build (edge structure is layer-invariant; rebuilt every launch)
    k_zero<<<(Rk*Nk + 255)/256, 256, 0, stream>>>(deg, Rk*Nk);
    k_count<<<(Rk*Ek + 255)/256, 256, 0, stream>>>(edge_index, deg);
    k_scan<<<Rk, 1024, 0, stream>>>(deg, offs, cursor);
    k_fill<<<(Rk*Ek + 255)/256, 256, 0, stream>>>(edge_index, edge_w, cursor, epack);

    // weight prep for MFMA projection (all layers at once)
    k_wprep<<<(Lk*4*2*4*64*8 + 255)/256, 256, 0, stream>>>(Wself, Wrel, wt);

    // FiLM
    k_film1<<<Bk*64, 256, 0, stream>>>(drug_fp, W_f1, b_f1, hid);
    k_film2<<<Bk, 128, 0, stream>>>(hid, W_f2, b_f2, g1p, beta);

    // x0
    k_init<<<2048, 256, 0, stream>>>(ctl, dt, cell_idx, W_se, b_se, cell_emb, g1p, beta, xh);

    // layers
    for(int l = 0; l < Lk; ++l){
        // 4 bpairs x 7500 groups x 4 waves; bpair=blockIdx&3 -> 2.56MB XCD slice
        k_agg<<<4*7500, 256, 0, stream>>>(xh, offs, epack, aggh);
        k_proj_mfma<<<dim3((Nk + 63)/64, Bk), 256, 0, stream>>>(
            xh, aggh, wt, ln_g, ln_b, l,
            (l == Lk-1) ? 1 : 0, W_out, b_out, out);
    }
}